// Round 1
// baseline (1784.867 us; speedup 1.0000x reference)
//
#include <hip/hip_runtime.h>
#include <stdint.h>

typedef unsigned short u16;
typedef __attribute__((ext_vector_type(4))) float f32x4;
typedef __attribute__((ext_vector_type(8))) short short8;
typedef __attribute__((ext_vector_type(4))) unsigned short u16x4;

__device__ __forceinline__ u16 f2b(float f) {
  uint32_t u = __float_as_uint(f);
  uint32_t r = (u + 0x7fffu + ((u >> 16) & 1u)) >> 16;   // RNE
  return (u16)r;
}
__device__ __forceinline__ float b2f(u16 b) {
  return __uint_as_float(((uint32_t)b) << 16);
}
__device__ __forceinline__ float sigm(float x) { return 1.f / (1.f + __expf(-x)); }
__device__ __forceinline__ float tanh_fast(float x) {
  float e = __expf(2.f * x);
  return 1.f - 2.f / (e + 1.f);   // safe at +-inf
}
__device__ __forceinline__ void gl2lds16(const void* g, void* l) {
  __builtin_amdgcn_global_load_lds((const __attribute__((address_space(1))) void*)g,
                                   (__attribute__((address_space(3))) void*)l, 16, 0, 0);
}

// ---------------- elementwise fp32 -> bf16 (frames) ----------------
__global__ void cvt_bf16_kernel(const float* __restrict__ in, u16* __restrict__ out, int n4) {
  int i = blockIdx.x * 256 + threadIdx.x;
  if (i >= n4) return;
  float4 v = ((const float4*)in)[i];
  u16x4 o = { f2b(v.x), f2b(v.y), f2b(v.z), f2b(v.w) };
  *(u16x4*)(out + (size_t)i * 4) = o;
}

// ---------------- W transpose + gate permutation ----------------
// out[p][kc], p in [0,2048): orig col = (p&3)*512 + (p>>2)  (gate-interleave)
// k_orig = kc < xpad ? kc : kc - (xpad - xreal); kc in [xreal,xpad) -> 0 pad
__global__ void transpose_perm_kernel(const float* __restrict__ W, u16* __restrict__ WT,
                                      int ldin, int ldout, int xreal, int xpad) {
  __shared__ float tile[64][65];
  const int kb = blockIdx.x * 64;   // output col (k) base
  const int pb = blockIdx.y * 64;   // output row (p) base
  const int t = threadIdx.x;
  const int g = t >> 6;             // 0..3 gate
  const int u = t & 63;
  const int colh = u & 15;
  const int krow4 = u >> 4;
  const int h0 = pb >> 2;
#pragma unroll
  for (int it = 0; it < 16; ++it) {
    int kl = krow4 + it * 4;
    int kc = kb + kl;
    int ko = kc < xpad ? kc : kc - (xpad - xreal);
    bool valid = (kc < xreal) || (kc >= xpad);
    float v = valid ? W[(size_t)ko * ldin + g * 512 + h0 + colh] : 0.f;
    tile[kl][4 * colh + g] = v;
  }
  __syncthreads();
  const int pl = t >> 2;
  const int kq = t & 3;
#pragma unroll
  for (int half = 0; half < 2; ++half) {
    union { short8 v; u16 a[8]; } pk;
#pragma unroll
    for (int i = 0; i < 8; ++i) pk.a[i] = f2b(tile[kq * 16 + half * 8 + i][pl]);
    *(short8*)&WT[(size_t)(pb + pl) * ldout + kb + kq * 16 + half * 8] = pk.v;
  }
}

// ---------------- W_out -> B^T bf16 [384][512] (rows >=300 zero) ----------------
__global__ void woutT_kernel(const float* __restrict__ Wout, u16* __restrict__ WT) {
  int idx = blockIdx.x * 256 + threadIdx.x;
  if (idx >= 384 * 512) return;
  int n = idx >> 9, k = idx & 511;
  float v = (n < 300) ? Wout[(size_t)k * 300 + n] : 0.f;
  WT[idx] = f2b(v);
}

// ---------------- embedding gather -> A_dec bf16 [4096][320] time-major ----------------
__global__ void embed_kernel(const int* __restrict__ ids, const float* __restrict__ emb,
                             u16* __restrict__ Adec) {
  int r = blockIdx.x;              // r = t*128 + b
  int t = r >> 7, b = r & 127;
  int id = ids[b * 32 + t];
  const float* src = emb + (size_t)id * 300;
  u16* dst = Adec + (size_t)r * 320;
  for (int d = threadIdx.x; d < 320; d += 64)
    dst[d] = f2b(d < 300 ? src[d] : 0.f);
}

// ---------------- m97-style bf16 GEMM: C = A[M][K] @ BT[N][K]^T ----------------
// MODE 0: enc pre  (bf16 out, row b*64+t -> t*128+b, permuted bias)
// MODE 1: dec pre  (bf16 out, identity rows, permuted bias)
// MODE 2: out proj (fp32 out, row t*128+b -> (b*32+t)*300+w, w<300 guard)
template <int MODE>
__global__ __launch_bounds__(256)
void gemm_kernel(const u16* __restrict__ A, int lda,
                 const u16* __restrict__ BT, int ldb,
                 void* __restrict__ Cv, const float* __restrict__ bias, int K) {
  __shared__ u16 atile[128 * 32];
  __shared__ u16 btile[128 * 32];
  const int tid = threadIdx.x;
  const int wave = tid >> 6;
  const int lane = tid & 63;
  const int m0 = blockIdx.x * 128;
  const int n0 = blockIdx.y * 128;
  const int wm = wave & 1;
  const int wn = wave >> 1;
  const int colq = lane & 15;
  const int rquad = lane >> 4;

  f32x4 acc[4][4];
#pragma unroll
  for (int i = 0; i < 4; ++i)
#pragma unroll
    for (int j = 0; j < 4; ++j) { f32x4 z = {0.f, 0.f, 0.f, 0.f}; acc[i][j] = z; }

  for (int k0 = 0; k0 < K; k0 += 32) {
#pragma unroll
    for (int c = 0; c < 2; ++c) {
      const int ch = wave + c * 4;            // chunk 0..7, 1KB each
      const int slot = ch * 64 + lane;        // 0..511
      const int m = slot >> 2;
      const int koff = (slot & 3) * 8;
      gl2lds16(A + (size_t)(m0 + m) * lda + k0 + koff, atile + ch * 512);
      gl2lds16(BT + (size_t)(n0 + m) * ldb + k0 + koff, btile + ch * 512);
    }
    __builtin_amdgcn_s_waitcnt(0);
    __syncthreads();
    short8 af[4], bf[4];
#pragma unroll
    for (int i = 0; i < 4; ++i)
      af[i] = *(const short8*)(atile + (wm * 64 + i * 16 + colq) * 32 + rquad * 8);
#pragma unroll
    for (int j = 0; j < 4; ++j)
      bf[j] = *(const short8*)(btile + (wn * 64 + j * 16 + colq) * 32 + rquad * 8);
#pragma unroll
    for (int i = 0; i < 4; ++i)
#pragma unroll
      for (int j = 0; j < 4; ++j)
        acc[i][j] = __builtin_amdgcn_mfma_f32_16x16x32_bf16(af[i], bf[j], acc[i][j], 0, 0, 0);
    __syncthreads();
  }

  const int gm_base = m0 + wm * 64;
  const int gn_base = n0 + wn * 64;
#pragma unroll
  for (int i = 0; i < 4; ++i) {
#pragma unroll
    for (int j = 0; j < 4; ++j) {
      const int gn = gn_base + j * 16 + colq;
      float bv;
      if (MODE == 2) bv = (gn < 300) ? bias[gn] : 0.f;
      else bv = bias[((gn & 3) << 9) + (gn >> 2)];
      const int rbase = gm_base + i * 16 + rquad * 4;
#pragma unroll
      for (int r = 0; r < 4; ++r) {
        const float v = acc[i][j][r] + bv;
        const int row = rbase + r;
        if (MODE == 0) {
          ((u16*)Cv)[(size_t)((row & 63) * 128 + (row >> 6)) * 2048 + gn] = f2b(v);
        } else if (MODE == 1) {
          ((u16*)Cv)[(size_t)row * 2048 + gn] = f2b(v);
        } else {
          if (gn < 300)
            ((float*)Cv)[(size_t)((row & 127) * 32 + (row >> 7)) * 300 + gn] = v;
        }
      }
    }
  }
}

// ---------------- persistent recurrent LSTM kernel ----------------
// 128 wgs = 4 batch-groups(32 rows) x 32 H-groups(16 h-cols = 64 permuted gate-cols)
// W_h slice resident in LDS; h ping-pongs via LLC with per-step release flags.
#define FLAG_IDX(s, bg, hg) (((s) * 4 + (bg)) * 32 + (hg))

__global__ __launch_bounds__(256, 1)
void lstm_recurrent_kernel(const u16* __restrict__ pre_enc,   // [64][128][2048] bf16
                           const u16* __restrict__ pre_dec,   // [32][128][2048] bf16
                           const u16* __restrict__ WencT,     // [2048][2560] bf16
                           const u16* __restrict__ WdecT,     // [2048][832]  bf16
                           u16* __restrict__ h_pp,            // [2][128][512] bf16 (zeroed)
                           u16* __restrict__ dec_hs,          // [32][128][512] bf16
                           int* __restrict__ flags) {         // [97][4][32]   (zeroed)
  const int tid = threadIdx.x;
  const int wave = tid >> 6;
  const int lane = tid & 63;
  const int bg = blockIdx.x & 3;
  const int hg = blockIdx.x >> 2;
  const int b0 = bg * 32;
  const int mt = wave & 1;            // 16-row m-tile within the 32-row bg
  const int nt0 = (wave >> 1) * 2;    // two 16-col n-tiles
  const int colq = lane & 15;
  const int rquad = lane >> 4;
  const int laneg = lane & 3;

  __shared__ u16 wlds[64][520];       // [gate-col local][k], +8 pad

  {  // encoder W_h slice: WencT rows hg*64.., cols 2048..2559
    const u16* src = WencT + (size_t)(hg * 64) * 2560 + 2048;
    for (int i = tid; i < 64 * 64; i += 256) {
      int row = i >> 6, cc = i & 63;
      *(short8*)&wlds[row][cc * 8] = *(const short8*)(src + (size_t)row * 2560 + cc * 8);
    }
  }
  __syncthreads();

  float cst[2][4];
#pragma unroll
  for (int l = 0; l < 2; ++l)
#pragma unroll
    for (int r = 0; r < 4; ++r) cst[l][r] = 0.f;

  const int brow_base = b0 + mt * 16 + rquad * 4;

  for (int s = 0; s < 96; ++s) {
    const bool dec = (s >= 64);
    const u16* pre_t = dec ? (pre_dec + (size_t)(s - 64) * 128 * 2048)
                           : (pre_enc + (size_t)s * 128 * 2048);
    // acc init from pre-activations (independent of h -> issue before the wait)
    f32x4 acc[2];
#pragma unroll
    for (int l = 0; l < 2; ++l) {
      const int pcol = hg * 64 + (nt0 + l) * 16 + colq;
#pragma unroll
      for (int r = 0; r < 4; ++r)
        acc[l][r] = b2f(pre_t[(size_t)(brow_base + r) * 2048 + pcol]);
    }
    if (s > 0) {
      int* fp = flags + FLAG_IDX(s, bg, tid & 31);
      while (__hip_atomic_load(fp, __ATOMIC_RELAXED, __HIP_MEMORY_SCOPE_AGENT) == 0)
        __builtin_amdgcn_s_sleep(1);
      __threadfence();   // acquire: invalidate L1/L2 so h reads hit LLC
    }
    __syncthreads();

    const u16* hread = h_pp + (size_t)(s & 1) * 128 * 512 + (size_t)(b0 + mt * 16 + colq) * 512;
#pragma unroll
    for (int kt = 0; kt < 16; ++kt) {
      short8 af = *(const short8*)(hread + kt * 32 + rquad * 8);
      short8 bf0 = *(const short8*)&wlds[nt0 * 16 + colq][kt * 32 + rquad * 8];
      short8 bf1 = *(const short8*)&wlds[nt0 * 16 + 16 + colq][kt * 32 + rquad * 8];
      acc[0] = __builtin_amdgcn_mfma_f32_16x16x32_bf16(af, bf0, acc[0], 0, 0, 0);
      acc[1] = __builtin_amdgcn_mfma_f32_16x16x32_bf16(af, bf1, acc[1], 0, 0, 0);
    }

    u16* hw = h_pp + (size_t)((s + 1) & 1) * 128 * 512;
    const int srcbase = lane & ~3;
#pragma unroll
    for (int l = 0; l < 2; ++l) {
      float hv[4];
#pragma unroll
      for (int r = 0; r < 4; ++r) {
        float v = acc[l][r];
        float iv = __shfl(v, srcbase + 0, 64);
        float jv = __shfl(v, srcbase + 1, 64);
        float fv = __shfl(v, srcbase + 2, 64);
        float ov = __shfl(v, srcbase + 3, 64);
        float cn = cst[l][r] * sigm(fv + 1.f) + sigm(iv) * tanh_fast(jv);
        cst[l][r] = cn;
        hv[r] = tanh_fast(cn) * sigm(ov);
      }
      if (laneg == 0) {
        const int hcol = hg * 16 + (nt0 + l) * 4 + (colq >> 2);
#pragma unroll
        for (int r = 0; r < 4; ++r) {
          u16 uu = f2b(hv[r]);
          hw[(size_t)(brow_base + r) * 512 + hcol] = uu;
          if (dec)
            dec_hs[(size_t)(s - 64) * 128 * 512 + (size_t)(brow_base + r) * 512 + hcol] = uu;
        }
      }
    }
    __syncthreads();                  // drains each thread's stores to L2
    if (s < 95 && tid == 0) {
      __threadfence();                // release: wbl2 -> LLC
      __hip_atomic_store(flags + FLAG_IDX(s + 1, bg, hg), 1,
                         __ATOMIC_RELAXED, __HIP_MEMORY_SCOPE_AGENT);
    }
    if (s == 63) {                    // swap to decoder W_h (cols 320..831 of WdecT)
      __syncthreads();
      const u16* src = WdecT + (size_t)(hg * 64) * 832 + 320;
      for (int i = tid; i < 64 * 64; i += 256) {
        int row = i >> 6, cc = i & 63;
        *(short8*)&wlds[row][cc * 8] = *(const short8*)(src + (size_t)row * 832 + cc * 8);
      }
      __syncthreads();
    }
  }
}

extern "C" void kernel_launch(void* const* d_in, const int* in_sizes, int n_in,
                              void* d_out, int out_size, void* d_ws, size_t ws_size,
                              hipStream_t stream) {
  const float* frames = (const float*)d_in[0];   // [128,64,2048]
  const int* cap_ids  = (const int*)d_in[1];     // [128,32]
  const float* emb    = (const float*)d_in[2];   // [32000,300]
  const float* W_enc  = (const float*)d_in[3];   // [2560,2048]
  const float* b_enc  = (const float*)d_in[4];   // [2048]
  const float* W_dec  = (const float*)d_in[5];   // [812,2048]
  const float* b_dec  = (const float*)d_in[6];   // [2048]
  const float* W_out  = (const float*)d_in[7];   // [512,300]
  const float* b_out  = (const float*)d_in[8];   // [300]
  float* out = (float*)d_out;

  char* ws = (char*)d_ws;
  size_t off = 0;
  auto alloc = [&](size_t bytes) {
    void* p = ws + off;
    off += (bytes + 255) & ~(size_t)255;
    return p;
  };
  u16* A_enc   = (u16*)alloc(8192ull * 2048 * 2);
  u16* WencT   = (u16*)alloc(2048ull * 2560 * 2);
  u16* pre_enc = (u16*)alloc(64ull * 128 * 2048 * 2);
  u16* A_dec   = (u16*)alloc(4096ull * 320 * 2);
  u16* WdecT   = (u16*)alloc(2048ull * 832 * 2);
  u16* pre_dec = (u16*)alloc(32ull * 128 * 2048 * 2);
  u16* WoutT   = (u16*)alloc(384ull * 512 * 2);
  u16* dec_hs  = (u16*)alloc(32ull * 128 * 512 * 2);
  u16* h_pp    = (u16*)alloc(2ull * 128 * 512 * 2);
  int* flags   = (int*)alloc(97ull * 4 * 32 * 4);

  hipMemsetAsync(h_pp, 0, 2ull * 128 * 512 * 2, stream);
  hipMemsetAsync(flags, 0, 97ull * 4 * 32 * 4, stream);

  cvt_bf16_kernel<<<16384, 256, 0, stream>>>(frames, A_enc, 4194304);
  transpose_perm_kernel<<<dim3(40, 32), 256, 0, stream>>>(W_enc, WencT, 2048, 2560, 2048, 2048);
  transpose_perm_kernel<<<dim3(13, 32), 256, 0, stream>>>(W_dec, WdecT, 2048, 832, 300, 320);
  woutT_kernel<<<768, 256, 0, stream>>>(W_out, WoutT);
  embed_kernel<<<4096, 64, 0, stream>>>(cap_ids, emb, A_dec);

  gemm_kernel<0><<<dim3(64, 16), 256, 0, stream>>>(A_enc, 2048, WencT, 2560, pre_enc, b_enc, 2048);
  gemm_kernel<1><<<dim3(32, 16), 256, 0, stream>>>(A_dec, 320, WdecT, 832, pre_dec, b_dec, 320);

  lstm_recurrent_kernel<<<128, 256, 0, stream>>>(pre_enc, pre_dec, WencT, WdecT,
                                                 h_pp, dec_hs, flags);

  gemm_kernel<2><<<dim3(32, 3), 256, 0, stream>>>(dec_hs, 512, WoutT, 512, out, b_out, 512);
}

// Round 2
// 1467.215 us; speedup vs baseline: 1.2165x; 1.2165x over previous
//
#include <hip/hip_runtime.h>
#include <stdint.h>

typedef unsigned short u16;
typedef __attribute__((ext_vector_type(4))) float f32x4;
typedef __attribute__((ext_vector_type(8))) short short8;
typedef __attribute__((ext_vector_type(4))) unsigned short u16x4;

__device__ __forceinline__ u16 f2b(float f) {
  uint32_t u = __float_as_uint(f);
  uint32_t r = (u + 0x7fffu + ((u >> 16) & 1u)) >> 16;   // RNE
  return (u16)r;
}
__device__ __forceinline__ float b2f(u16 b) {
  return __uint_as_float(((uint32_t)b) << 16);
}
__device__ __forceinline__ float sigm(float x) { return 1.f / (1.f + __expf(-x)); }
__device__ __forceinline__ float tanh_fast(float x) {
  float e = __expf(2.f * x);
  return 1.f - 2.f / (e + 1.f);   // safe at +-inf
}
__device__ __forceinline__ void gl2lds16(const void* g, void* l) {
  __builtin_amdgcn_global_load_lds((const __attribute__((address_space(1))) void*)g,
                                   (__attribute__((address_space(3))) void*)l, 16, 0, 0);
}

// ---------------- elementwise fp32 -> bf16 (frames) ----------------
__global__ void cvt_bf16_kernel(const float* __restrict__ in, u16* __restrict__ out, int n4) {
  int i = blockIdx.x * 256 + threadIdx.x;
  if (i >= n4) return;
  float4 v = ((const float4*)in)[i];
  u16x4 o = { f2b(v.x), f2b(v.y), f2b(v.z), f2b(v.w) };
  *(u16x4*)(out + (size_t)i * 4) = o;
}

// ---------------- W transpose + gate permutation ----------------
// out[p][kc], p in [0,2048): orig col = (p&3)*512 + (p>>2)  (gate-interleave)
__global__ void transpose_perm_kernel(const float* __restrict__ W, u16* __restrict__ WT,
                                      int ldin, int ldout, int xreal, int xpad) {
  __shared__ float tile[64][65];
  const int kb = blockIdx.x * 64;
  const int pb = blockIdx.y * 64;
  const int t = threadIdx.x;
  const int g = t >> 6;
  const int u = t & 63;
  const int colh = u & 15;
  const int krow4 = u >> 4;
  const int h0 = pb >> 2;
#pragma unroll
  for (int it = 0; it < 16; ++it) {
    int kl = krow4 + it * 4;
    int kc = kb + kl;
    int ko = kc < xpad ? kc : kc - (xpad - xreal);
    bool valid = (kc < xreal) || (kc >= xpad);
    float v = valid ? W[(size_t)ko * ldin + g * 512 + h0 + colh] : 0.f;
    tile[kl][4 * colh + g] = v;
  }
  __syncthreads();
  const int pl = t >> 2;
  const int kq = t & 3;
#pragma unroll
  for (int half = 0; half < 2; ++half) {
    union { short8 v; u16 a[8]; } pk;
#pragma unroll
    for (int i = 0; i < 8; ++i) pk.a[i] = f2b(tile[kq * 16 + half * 8 + i][pl]);
    *(short8*)&WT[(size_t)(pb + pl) * ldout + kb + kq * 16 + half * 8] = pk.v;
  }
}

// ---------------- W_out -> B^T bf16 [384][512] (rows >=300 zero) ----------------
__global__ void woutT_kernel(const float* __restrict__ Wout, u16* __restrict__ WT) {
  int idx = blockIdx.x * 256 + threadIdx.x;
  if (idx >= 384 * 512) return;
  int n = idx >> 9, k = idx & 511;
  float v = (n < 300) ? Wout[(size_t)k * 300 + n] : 0.f;
  WT[idx] = f2b(v);
}

// ---------------- embedding gather -> A_dec bf16 [4096][320] time-major ----------------
__global__ void embed_kernel(const int* __restrict__ ids, const float* __restrict__ emb,
                             u16* __restrict__ Adec) {
  int r = blockIdx.x;              // r = t*128 + b
  int t = r >> 7, b = r & 127;
  int id = ids[b * 32 + t];
  const float* src = emb + (size_t)id * 300;
  u16* dst = Adec + (size_t)r * 320;
  for (int d = threadIdx.x; d < 320; d += 64)
    dst[d] = f2b(d < 300 ? src[d] : 0.f);
}

// ---------------- m97-style bf16 GEMM: C = A[M][K] @ BT[N][K]^T ----------------
template <int MODE>
__global__ __launch_bounds__(256)
void gemm_kernel(const u16* __restrict__ A, int lda,
                 const u16* __restrict__ BT, int ldb,
                 void* __restrict__ Cv, const float* __restrict__ bias, int K) {
  __shared__ u16 atile[128 * 32];
  __shared__ u16 btile[128 * 32];
  const int tid = threadIdx.x;
  const int wave = tid >> 6;
  const int lane = tid & 63;
  const int m0 = blockIdx.x * 128;
  const int n0 = blockIdx.y * 128;
  const int wm = wave & 1;
  const int wn = wave >> 1;
  const int colq = lane & 15;
  const int rquad = lane >> 4;

  f32x4 acc[4][4];
#pragma unroll
  for (int i = 0; i < 4; ++i)
#pragma unroll
    for (int j = 0; j < 4; ++j) { f32x4 z = {0.f, 0.f, 0.f, 0.f}; acc[i][j] = z; }

  for (int k0 = 0; k0 < K; k0 += 32) {
#pragma unroll
    for (int c = 0; c < 2; ++c) {
      const int ch = wave + c * 4;
      const int slot = ch * 64 + lane;
      const int m = slot >> 2;
      const int koff = (slot & 3) * 8;
      gl2lds16(A + (size_t)(m0 + m) * lda + k0 + koff, atile + ch * 512);
      gl2lds16(BT + (size_t)(n0 + m) * ldb + k0 + koff, btile + ch * 512);
    }
    __builtin_amdgcn_s_waitcnt(0);
    __syncthreads();
    short8 af[4], bf[4];
#pragma unroll
    for (int i = 0; i < 4; ++i)
      af[i] = *(const short8*)(atile + (wm * 64 + i * 16 + colq) * 32 + rquad * 8);
#pragma unroll
    for (int j = 0; j < 4; ++j)
      bf[j] = *(const short8*)(btile + (wn * 64 + j * 16 + colq) * 32 + rquad * 8);
#pragma unroll
    for (int i = 0; i < 4; ++i)
#pragma unroll
      for (int j = 0; j < 4; ++j)
        acc[i][j] = __builtin_amdgcn_mfma_f32_16x16x32_bf16(af[i], bf[j], acc[i][j], 0, 0, 0);
    __syncthreads();
  }

  const int gm_base = m0 + wm * 64;
  const int gn_base = n0 + wn * 64;
#pragma unroll
  for (int i = 0; i < 4; ++i) {
#pragma unroll
    for (int j = 0; j < 4; ++j) {
      const int gn = gn_base + j * 16 + colq;
      float bv;
      if (MODE == 2) bv = (gn < 300) ? bias[gn] : 0.f;
      else bv = bias[((gn & 3) << 9) + (gn >> 2)];
      const int rbase = gm_base + i * 16 + rquad * 4;
#pragma unroll
      for (int r = 0; r < 4; ++r) {
        const float v = acc[i][j][r] + bv;
        const int row = rbase + r;
        if (MODE == 0) {
          ((u16*)Cv)[(size_t)((row & 63) * 128 + (row >> 6)) * 2048 + gn] = f2b(v);
        } else if (MODE == 1) {
          ((u16*)Cv)[(size_t)row * 2048 + gn] = f2b(v);
        } else {
          if (gn < 300)
            ((float*)Cv)[(size_t)((row & 127) * 32 + (row >> 7)) * 300 + gn] = v;
        }
      }
    }
  }
}

// ---------------- persistent recurrent LSTM kernel ----------------
// 64 wgs = 4 batch-groups(32 rows) x 16 H-groups(32 h-cols = 128 permuted gate-cols)
// W_h slice (128x512 bf16 = 130KB) resident in LDS for all 96 steps.
// h exchange: packed-u32 relaxed agent atomics (write-through LLC, NO fences),
// per-producer flags; __syncthreads() provides the vmcnt(0) drain before flag set.
__global__ __launch_bounds__(256, 1)
void lstm_recurrent_kernel(const u16* __restrict__ pre_enc,   // [64][128][2048] bf16
                           const u16* __restrict__ pre_dec,   // [32][128][2048] bf16
                           const u16* __restrict__ WencT,     // [2048][2560] bf16
                           const u16* __restrict__ WdecT,     // [2048][832]  bf16
                           int* __restrict__ h32,             // [2][128][256] u32 pairs (zeroed)
                           u16* __restrict__ dec_hs,          // [32][128][512] bf16
                           int* __restrict__ flags) {         // [97][4][16]   (zeroed)
  const int tid = threadIdx.x;
  const int wave = tid >> 6;
  const int lane = tid & 63;
  const int bg = blockIdx.x & 3;
  const int hg = blockIdx.x >> 2;       // 0..15
  const int b0 = bg * 32;
  const int mt = wave & 1;              // 16-row m-tile
  const int ntb = (wave >> 1) * 4;      // four 16-gate-col n-tiles per wave
  const int colq = lane & 15;
  const int rquad = lane >> 4;

  __shared__ u16 wlds[128][520];        // [gate-col local][k], +8 pad

  {  // encoder W_h slice: WencT rows hg*128.., cols 2048..2559
    const u16* src = WencT + (size_t)(hg * 128) * 2560 + 2048;
    for (int i = tid; i < 128 * 64; i += 256) {
      int row = i >> 6, cc = i & 63;
      *(short8*)&wlds[row][cc * 8] = *(const short8*)(src + (size_t)row * 2560 + cc * 8);
    }
  }
  __syncthreads();

  float cst[4][4];
#pragma unroll
  for (int l = 0; l < 4; ++l)
#pragma unroll
    for (int r = 0; r < 4; ++r) cst[l][r] = 0.f;

  const int brow_base = b0 + mt * 16 + rquad * 4;   // C-layout rows
  const int rowA = b0 + mt * 16 + colq;             // A-layout row (h read)
  const int srcbase = lane & ~3;
  int* dechs32 = (int*)dec_hs;

  for (int s = 0; s < 96; ++s) {
    const bool dec = (s >= 64);
    const u16* pre_t = dec ? (pre_dec + (size_t)(s - 64) * 128 * 2048)
                           : (pre_enc + (size_t)s * 128 * 2048);
    // acc init from pre-activations (plain cached loads, issued before the wait)
    f32x4 acc[4];
#pragma unroll
    for (int l = 0; l < 4; ++l) {
      const int pcol = hg * 128 + (ntb + l) * 16 + colq;
#pragma unroll
      for (int r = 0; r < 4; ++r)
        acc[l][r] = b2f(pre_t[(size_t)(brow_base + r) * 2048 + pcol]);
    }
    if (s > 0 && tid < 16) {
      const int* fp = flags + (s * 4 + bg) * 16 + tid;
      while (__hip_atomic_load(fp, __ATOMIC_RELAXED, __HIP_MEMORY_SCOPE_AGENT) == 0)
        __builtin_amdgcn_s_sleep(1);
    }
    __syncthreads();   // join poll; orders subsequent h loads after flag observation

    // h @ W_h  (h read as packed u32 pairs via coherent relaxed atomics)
    const int* hread = h32 + (size_t)(s & 1) * 128 * 256 + rowA * 256;
#pragma unroll
    for (int kt = 0; kt < 16; ++kt) {
      union { short8 v; int i[4]; } af;
#pragma unroll
      for (int j = 0; j < 4; ++j)
        af.i[j] = __hip_atomic_load(hread + kt * 16 + rquad * 4 + j,
                                    __ATOMIC_RELAXED, __HIP_MEMORY_SCOPE_AGENT);
#pragma unroll
      for (int l = 0; l < 4; ++l) {
        short8 bf = *(const short8*)&wlds[(ntb + l) * 16 + colq][kt * 32 + rquad * 8];
        acc[l] = __builtin_amdgcn_mfma_f32_16x16x32_bf16(af.v, bf, acc[l], 0, 0, 0);
      }
    }

    // elementwise gates + h/c update + packed store
    int* hw = h32 + (size_t)((s + 1) & 1) * 128 * 256;
#pragma unroll
    for (int l = 0; l < 4; ++l) {
      const int nt = ntb + l;
#pragma unroll
      for (int r = 0; r < 4; ++r) {
        float v = acc[l][r];
        float iv = __shfl(v, srcbase + 0, 64);
        float jv = __shfl(v, srcbase + 1, 64);
        float fv = __shfl(v, srcbase + 2, 64);
        float ov = __shfl(v, srcbase + 3, 64);
        float cn = cst[l][r] * sigm(fv + 1.f) + sigm(iv) * tanh_fast(jv);
        cst[l][r] = cn;
        float hvv = tanh_fast(cn) * sigm(ov);
        float pv = __shfl(hvv, lane + 4, 64);   // partner h-col (colq+4)
        uint32_t packed = (uint32_t)f2b(hvv) | ((uint32_t)f2b(pv) << 16);
        if ((lane & 7) == 0) {                  // colq in {0,8}: even h-col lanes
          int idx = (brow_base + r) * 256 + hg * 16 + nt * 2 + (colq >> 3);
          __hip_atomic_store(hw + idx, (int)packed,
                             __ATOMIC_RELAXED, __HIP_MEMORY_SCOPE_AGENT);
          if (dec)
            dechs32[(size_t)(s - 64) * 128 * 256 + idx] = (int)packed;
        }
      }
    }
    __syncthreads();   // emits s_waitcnt vmcnt(0): all wg h stores are at LLC
    if (s < 95 && tid == 0) {
      __hip_atomic_store(flags + ((s + 1) * 4 + bg) * 16 + hg, 1,
                         __ATOMIC_RELAXED, __HIP_MEMORY_SCOPE_AGENT);
    }
    if (s == 63) {     // swap to decoder W_h (cols 320..831 of WdecT)
      __syncthreads();
      const u16* src = WdecT + (size_t)(hg * 128) * 832 + 320;
      for (int i = tid; i < 128 * 64; i += 256) {
        int row = i >> 6, cc = i & 63;
        *(short8*)&wlds[row][cc * 8] = *(const short8*)(src + (size_t)row * 832 + cc * 8);
      }
      __syncthreads();
    }
  }
}

extern "C" void kernel_launch(void* const* d_in, const int* in_sizes, int n_in,
                              void* d_out, int out_size, void* d_ws, size_t ws_size,
                              hipStream_t stream) {
  const float* frames = (const float*)d_in[0];   // [128,64,2048]
  const int* cap_ids  = (const int*)d_in[1];     // [128,32]
  const float* emb    = (const float*)d_in[2];   // [32000,300]
  const float* W_enc  = (const float*)d_in[3];   // [2560,2048]
  const float* b_enc  = (const float*)d_in[4];   // [2048]
  const float* W_dec  = (const float*)d_in[5];   // [812,2048]
  const float* b_dec  = (const float*)d_in[6];   // [2048]
  const float* W_out  = (const float*)d_in[7];   // [512,300]
  const float* b_out  = (const float*)d_in[8];   // [300]
  float* out = (float*)d_out;

  char* ws = (char*)d_ws;
  size_t off = 0;
  auto alloc = [&](size_t bytes) {
    void* p = ws + off;
    off += (bytes + 255) & ~(size_t)255;
    return p;
  };
  u16* A_enc   = (u16*)alloc(8192ull * 2048 * 2);
  u16* WencT   = (u16*)alloc(2048ull * 2560 * 2);
  u16* pre_enc = (u16*)alloc(64ull * 128 * 2048 * 2);
  u16* A_dec   = (u16*)alloc(4096ull * 320 * 2);
  u16* WdecT   = (u16*)alloc(2048ull * 832 * 2);
  u16* pre_dec = (u16*)alloc(32ull * 128 * 2048 * 2);
  u16* WoutT   = (u16*)alloc(384ull * 512 * 2);
  u16* dec_hs  = (u16*)alloc(32ull * 128 * 512 * 2);
  int* h32     = (int*)alloc(2ull * 128 * 256 * 4);
  int* flags   = (int*)alloc(97ull * 4 * 16 * 4);

  hipMemsetAsync(h32, 0, 2ull * 128 * 256 * 4, stream);
  hipMemsetAsync(flags, 0, 97ull * 4 * 16 * 4, stream);

  cvt_bf16_kernel<<<16384, 256, 0, stream>>>(frames, A_enc, 4194304);
  transpose_perm_kernel<<<dim3(40, 32), 256, 0, stream>>>(W_enc, WencT, 2048, 2560, 2048, 2048);
  transpose_perm_kernel<<<dim3(13, 32), 256, 0, stream>>>(W_dec, WdecT, 2048, 832, 300, 320);
  woutT_kernel<<<768, 256, 0, stream>>>(W_out, WoutT);
  embed_kernel<<<4096, 64, 0, stream>>>(cap_ids, emb, A_dec);

  gemm_kernel<0><<<dim3(64, 16), 256, 0, stream>>>(A_enc, 2048, WencT, 2560, pre_enc, b_enc, 2048);
  gemm_kernel<1><<<dim3(32, 16), 256, 0, stream>>>(A_dec, 320, WdecT, 832, pre_dec, b_dec, 320);

  lstm_recurrent_kernel<<<64, 256, 0, stream>>>(pre_enc, pre_dec, WencT, WdecT,
                                                h32, dec_hs, flags);

  gemm_kernel<2><<<dim3(32, 3), 256, 0, stream>>>(dec_hs, 512, WoutT, 512, out, b_out, 512);
}

// Round 3
// 1184.523 us; speedup vs baseline: 1.5068x; 1.2387x over previous
//
#include <hip/hip_runtime.h>
#include <stdint.h>

typedef unsigned short u16;
typedef __attribute__((ext_vector_type(4))) float f32x4;
typedef __attribute__((ext_vector_type(8))) short short8;
typedef __attribute__((ext_vector_type(4))) unsigned short u16x4;
typedef __attribute__((ext_vector_type(4))) int int4v;

__device__ __forceinline__ u16 f2b(float f) {
  uint32_t u = __float_as_uint(f);
  uint32_t r = (u + 0x7fffu + ((u >> 16) & 1u)) >> 16;   // RNE
  return (u16)r;
}
__device__ __forceinline__ float b2f(u16 b) {
  return __uint_as_float(((uint32_t)b) << 16);
}
__device__ __forceinline__ float sigm(float x) { return 1.f / (1.f + __expf(-x)); }
__device__ __forceinline__ float tanh_fast(float x) {
  float e = __expf(2.f * x);
  return 1.f - 2.f / (e + 1.f);   // safe at +-inf
}
__device__ __forceinline__ void gl2lds16(const void* g, void* l) {
  __builtin_amdgcn_global_load_lds((const __attribute__((address_space(1))) void*)g,
                                   (__attribute__((address_space(3))) void*)l, 16, 0, 0);
}

// ---------------- elementwise fp32 -> bf16 (frames) ----------------
__global__ void cvt_bf16_kernel(const float* __restrict__ in, u16* __restrict__ out, int n4) {
  int i = blockIdx.x * 256 + threadIdx.x;
  if (i >= n4) return;
  float4 v = ((const float4*)in)[i];
  u16x4 o = { f2b(v.x), f2b(v.y), f2b(v.z), f2b(v.w) };
  *(u16x4*)(out + (size_t)i * 4) = o;
}

// ---------------- W transpose + gate permutation ----------------
// out[p][kc], p in [0,2048): orig col = (p&3)*512 + (p>>2)  (gate-interleave)
__global__ void transpose_perm_kernel(const float* __restrict__ W, u16* __restrict__ WT,
                                      int ldin, int ldout, int xreal, int xpad) {
  __shared__ float tile[64][65];
  const int kb = blockIdx.x * 64;
  const int pb = blockIdx.y * 64;
  const int t = threadIdx.x;
  const int g = t >> 6;
  const int u = t & 63;
  const int colh = u & 15;
  const int krow4 = u >> 4;
  const int h0 = pb >> 2;
#pragma unroll
  for (int it = 0; it < 16; ++it) {
    int kl = krow4 + it * 4;
    int kc = kb + kl;
    int ko = kc < xpad ? kc : kc - (xpad - xreal);
    bool valid = (kc < xreal) || (kc >= xpad);
    float v = valid ? W[(size_t)ko * ldin + g * 512 + h0 + colh] : 0.f;
    tile[kl][4 * colh + g] = v;
  }
  __syncthreads();
  const int pl = t >> 2;
  const int kq = t & 3;
#pragma unroll
  for (int half = 0; half < 2; ++half) {
    union { short8 v; u16 a[8]; } pk;
#pragma unroll
    for (int i = 0; i < 8; ++i) pk.a[i] = f2b(tile[kq * 16 + half * 8 + i][pl]);
    *(short8*)&WT[(size_t)(pb + pl) * ldout + kb + kq * 16 + half * 8] = pk.v;
  }
}

// ---------------- W_out -> B^T bf16 [384][512] (rows >=300 zero) ----------------
__global__ void woutT_kernel(const float* __restrict__ Wout, u16* __restrict__ WT) {
  int idx = blockIdx.x * 256 + threadIdx.x;
  if (idx >= 384 * 512) return;
  int n = idx >> 9, k = idx & 511;
  float v = (n < 300) ? Wout[(size_t)k * 300 + n] : 0.f;
  WT[idx] = f2b(v);
}

// ---------------- embedding gather -> A_dec bf16 [4096][320] time-major ----------------
__global__ void embed_kernel(const int* __restrict__ ids, const float* __restrict__ emb,
                             u16* __restrict__ Adec) {
  int r = blockIdx.x;              // r = t*128 + b
  int t = r >> 7, b = r & 127;
  int id = ids[b * 32 + t];
  const float* src = emb + (size_t)id * 300;
  u16* dst = Adec + (size_t)r * 320;
  for (int d = threadIdx.x; d < 320; d += 64)
    dst[d] = f2b(d < 300 ? src[d] : 0.f);
}

// ---------------- m97-style bf16 GEMM: C = A[M][K] @ BT[N][K]^T ----------------
template <int MODE>
__global__ __launch_bounds__(256)
void gemm_kernel(const u16* __restrict__ A, int lda,
                 const u16* __restrict__ BT, int ldb,
                 void* __restrict__ Cv, const float* __restrict__ bias, int K) {
  __shared__ u16 atile[128 * 32];
  __shared__ u16 btile[128 * 32];
  const int tid = threadIdx.x;
  const int wave = tid >> 6;
  const int lane = tid & 63;
  const int m0 = blockIdx.x * 128;
  const int n0 = blockIdx.y * 128;
  const int wm = wave & 1;
  const int wn = wave >> 1;
  const int colq = lane & 15;
  const int rquad = lane >> 4;

  f32x4 acc[4][4];
#pragma unroll
  for (int i = 0; i < 4; ++i)
#pragma unroll
    for (int j = 0; j < 4; ++j) { f32x4 z = {0.f, 0.f, 0.f, 0.f}; acc[i][j] = z; }

  for (int k0 = 0; k0 < K; k0 += 32) {
#pragma unroll
    for (int c = 0; c < 2; ++c) {
      const int ch = wave + c * 4;
      const int slot = ch * 64 + lane;
      const int m = slot >> 2;
      const int koff = (slot & 3) * 8;
      gl2lds16(A + (size_t)(m0 + m) * lda + k0 + koff, atile + ch * 512);
      gl2lds16(BT + (size_t)(n0 + m) * ldb + k0 + koff, btile + ch * 512);
    }
    __builtin_amdgcn_s_waitcnt(0);
    __syncthreads();
    short8 af[4], bf[4];
#pragma unroll
    for (int i = 0; i < 4; ++i)
      af[i] = *(const short8*)(atile + (wm * 64 + i * 16 + colq) * 32 + rquad * 8);
#pragma unroll
    for (int j = 0; j < 4; ++j)
      bf[j] = *(const short8*)(btile + (wn * 64 + j * 16 + colq) * 32 + rquad * 8);
#pragma unroll
    for (int i = 0; i < 4; ++i)
#pragma unroll
      for (int j = 0; j < 4; ++j)
        acc[i][j] = __builtin_amdgcn_mfma_f32_16x16x32_bf16(af[i], bf[j], acc[i][j], 0, 0, 0);
    __syncthreads();
  }

  const int gm_base = m0 + wm * 64;
  const int gn_base = n0 + wn * 64;
#pragma unroll
  for (int i = 0; i < 4; ++i) {
#pragma unroll
    for (int j = 0; j < 4; ++j) {
      const int gn = gn_base + j * 16 + colq;
      float bv;
      if (MODE == 2) bv = (gn < 300) ? bias[gn] : 0.f;
      else bv = bias[((gn & 3) << 9) + (gn >> 2)];
      const int rbase = gm_base + i * 16 + rquad * 4;
#pragma unroll
      for (int r = 0; r < 4; ++r) {
        const float v = acc[i][j][r] + bv;
        const int row = rbase + r;
        if (MODE == 0) {
          ((u16*)Cv)[(size_t)((row & 63) * 128 + (row >> 6)) * 2048 + gn] = f2b(v);
        } else if (MODE == 1) {
          ((u16*)Cv)[(size_t)row * 2048 + gn] = f2b(v);
        } else {
          if (gn < 300)
            ((float*)Cv)[(size_t)((row & 127) * 32 + (row >> 7)) * 300 + gn] = v;
        }
      }
    }
  }
}

// ---------------- persistent recurrent LSTM kernel ----------------
// 64 wgs = 4 batch-groups(32 rows) x 16 H-groups(32 h-cols = 128 permuted gate-cols)
// W_h slice (128x512 bf16 = 130KB) resident in LDS for all 96 steps.
// Sync protocol: NONE. Per-step h buffers hbuf[97][128][256 dwords]; buffers 1..96
// pre-filled with 0xFFFFFFFF canary (bf16 NaN, unreachable for h = tanh*sigm).
// Producers store h dwords via sc0/sc1 write-through asm stores; consumers poll the
// data itself with sc0/sc1 dwordx4 asm loads until every dword != canary.
// hbuf[65..96] doubles as the A matrix ([t*128+b][512] bf16) for the output GEMM.
__global__ __launch_bounds__(256, 1)
void lstm_recurrent_kernel(const u16* __restrict__ pre_enc,   // [64][128][2048] bf16
                           const u16* __restrict__ pre_dec,   // [32][128][2048] bf16
                           const u16* __restrict__ WencT,     // [2048][2560] bf16
                           const u16* __restrict__ WdecT,     // [2048][832]  bf16
                           int* __restrict__ hbuf) {          // [97][128][256] dwords
  const int tid = threadIdx.x;
  const int wave = tid >> 6;
  const int lane = tid & 63;
  const int bg = blockIdx.x & 3;
  const int hg = blockIdx.x >> 2;       // 0..15
  const int b0 = bg * 32;
  const int mt = wave & 1;              // 16-row m-tile
  const int ntb = (wave >> 1) * 4;      // four 16-gate-col n-tiles per wave
  const int colq = lane & 15;
  const int rquad = lane >> 4;

  __shared__ u16 wlds[128][520];        // [gate-col local][k], +8 pad

  {  // encoder W_h slice: WencT rows hg*128.., cols 2048..2559
    const u16* src = WencT + (size_t)(hg * 128) * 2560 + 2048;
    for (int i = tid; i < 128 * 64; i += 256) {
      int row = i >> 6, cc = i & 63;
      *(short8*)&wlds[row][cc * 8] = *(const short8*)(src + (size_t)row * 2560 + cc * 8);
    }
  }
  __syncthreads();

  float cst[4][4];
#pragma unroll
  for (int l = 0; l < 4; ++l)
#pragma unroll
    for (int r = 0; r < 4; ++r) cst[l][r] = 0.f;

  const int brow_base = b0 + mt * 16 + rquad * 4;   // C-layout rows
  const int rowA = b0 + mt * 16 + colq;             // A-layout row (h read)
  const int srcbase = lane & ~3;

  union HV { int4v i; short8 s; };
  HV hv[16];

  for (int s = 0; s < 96; ++s) {
    const bool dec = (s >= 64);
    const u16* pre_t = dec ? (pre_dec + (size_t)(s - 64) * 128 * 2048)
                           : (pre_enc + (size_t)s * 128 * 2048);
    // acc init from pre-activations (plain cached loads, overlap the poll)
    f32x4 acc[4];
#pragma unroll
    for (int l = 0; l < 4; ++l) {
      const int pcol = hg * 128 + (ntb + l) * 16 + colq;
#pragma unroll
      for (int r = 0; r < 4; ++r)
        acc[l][r] = b2f(pre_t[(size_t)(brow_base + r) * 2048 + pcol]);
    }

    // poll h(s): 16 x dwordx4 bypass loads, retry until no canary remains
    const int* hread = hbuf + (size_t)s * 32768 + rowA * 256 + rquad * 4;
    int bad;
    do {
#pragma unroll
      for (int kt = 0; kt < 16; ++kt)
        asm volatile("global_load_dwordx4 %0, %1, off offset:%2 sc0 sc1"
                     : "=v"(hv[kt].i) : "v"(hread), "i"(kt * 64) : "memory");
      asm volatile("s_waitcnt vmcnt(0)" ::: "memory");
      bad = 0;
#pragma unroll
      for (int kt = 0; kt < 16; ++kt)
#pragma unroll
        for (int j = 0; j < 4; ++j)
          bad |= (hv[kt].i[j] == -1) ? 1 : 0;
    } while (bad);

    // h @ W_h
#pragma unroll
    for (int kt = 0; kt < 16; ++kt) {
#pragma unroll
      for (int l = 0; l < 4; ++l) {
        short8 bf = *(const short8*)&wlds[(ntb + l) * 16 + colq][kt * 32 + rquad * 8];
        acc[l] = __builtin_amdgcn_mfma_f32_16x16x32_bf16(hv[kt].s, bf, acc[l], 0, 0, 0);
      }
    }

    // elementwise gates + h/c update + packed bypass store into hbuf[s+1]
    int* hw = hbuf + (size_t)(s + 1) * 32768;
#pragma unroll
    for (int l = 0; l < 4; ++l) {
      const int nt = ntb + l;
#pragma unroll
      for (int r = 0; r < 4; ++r) {
        float v = acc[l][r];
        float iv = __shfl(v, srcbase + 0, 64);
        float jv = __shfl(v, srcbase + 1, 64);
        float fv = __shfl(v, srcbase + 2, 64);
        float ov = __shfl(v, srcbase + 3, 64);
        float cn = cst[l][r] * sigm(fv + 1.f) + sigm(iv) * tanh_fast(jv);
        cst[l][r] = cn;
        float hvv = tanh_fast(cn) * sigm(ov);
        float pv = __shfl(hvv, lane + 4, 64);   // partner h-col (col+1)
        uint32_t packed = (uint32_t)f2b(hvv) | ((uint32_t)f2b(pv) << 16);
        if ((lane & 7) == 0) {                  // colq in {0,8}
          int* p = hw + (brow_base + r) * 256 + hg * 16 + nt * 2 + (colq >> 3);
          asm volatile("global_store_dword %0, %1, off sc0 sc1"
                       :: "v"(p), "v"((int)packed) : "memory");
        }
      }
    }

    if (s == 63) {     // swap to decoder W_h (cols 320..831 of WdecT)
      __syncthreads();
      const u16* src = WdecT + (size_t)(hg * 128) * 832 + 320;
      for (int i = tid; i < 128 * 64; i += 256) {
        int row = i >> 6, cc = i & 63;
        *(short8*)&wlds[row][cc * 8] = *(const short8*)(src + (size_t)row * 832 + cc * 8);
      }
      __syncthreads();
    }
  }
  asm volatile("s_waitcnt vmcnt(0)" ::: "memory");  // drain asm stores before endpgm
}

extern "C" void kernel_launch(void* const* d_in, const int* in_sizes, int n_in,
                              void* d_out, int out_size, void* d_ws, size_t ws_size,
                              hipStream_t stream) {
  const float* frames = (const float*)d_in[0];   // [128,64,2048]
  const int* cap_ids  = (const int*)d_in[1];     // [128,32]
  const float* emb    = (const float*)d_in[2];   // [32000,300]
  const float* W_enc  = (const float*)d_in[3];   // [2560,2048]
  const float* b_enc  = (const float*)d_in[4];   // [2048]
  const float* W_dec  = (const float*)d_in[5];   // [812,2048]
  const float* b_dec  = (const float*)d_in[6];   // [2048]
  const float* W_out  = (const float*)d_in[7];   // [512,300]
  const float* b_out  = (const float*)d_in[8];   // [300]
  float* out = (float*)d_out;

  char* ws = (char*)d_ws;
  size_t off = 0;
  auto alloc = [&](size_t bytes) {
    void* p = ws + off;
    off += (bytes + 255) & ~(size_t)255;
    return p;
  };
  u16* A_enc   = (u16*)alloc(8192ull * 2048 * 2);
  u16* WencT   = (u16*)alloc(2048ull * 2560 * 2);
  u16* pre_enc = (u16*)alloc(64ull * 128 * 2048 * 2);
  u16* A_dec   = (u16*)alloc(4096ull * 320 * 2);
  u16* WdecT   = (u16*)alloc(2048ull * 832 * 2);
  u16* pre_dec = (u16*)alloc(32ull * 128 * 2048 * 2);
  u16* WoutT   = (u16*)alloc(384ull * 512 * 2);
  int* hbuf    = (int*)alloc(97ull * 128 * 256 * 4);

  // hbuf[0] = h0 = zeros; hbuf[1..96] = 0xFFFFFFFF canary
  hipMemsetAsync(hbuf, 0, 128ull * 256 * 4, stream);
  hipMemsetAsync(hbuf + 128 * 256, 0xFF, 96ull * 128 * 256 * 4, stream);

  cvt_bf16_kernel<<<16384, 256, 0, stream>>>(frames, A_enc, 4194304);
  transpose_perm_kernel<<<dim3(40, 32), 256, 0, stream>>>(W_enc, WencT, 2048, 2560, 2048, 2048);
  transpose_perm_kernel<<<dim3(13, 32), 256, 0, stream>>>(W_dec, WdecT, 2048, 832, 300, 320);
  woutT_kernel<<<768, 256, 0, stream>>>(W_out, WoutT);
  embed_kernel<<<4096, 64, 0, stream>>>(cap_ids, emb, A_dec);

  gemm_kernel<0><<<dim3(64, 16), 256, 0, stream>>>(A_enc, 2048, WencT, 2560, pre_enc, b_enc, 2048);
  gemm_kernel<1><<<dim3(32, 16), 256, 0, stream>>>(A_dec, 320, WdecT, 832, pre_dec, b_dec, 320);

  lstm_recurrent_kernel<<<64, 256, 0, stream>>>(pre_enc, pre_dec, WencT, WdecT, hbuf);

  // decoder h outputs live at hbuf[65..96] == A[t*128+b][512] bf16
  gemm_kernel<2><<<dim3(32, 3), 256, 0, stream>>>((const u16*)hbuf + 65ull * 128 * 512, 512,
                                                  WoutT, 512, out, b_out, 512);
}

// Round 5
// 1177.924 us; speedup vs baseline: 1.5153x; 1.0056x over previous
//
#include <hip/hip_runtime.h>
#include <stdint.h>

typedef unsigned short u16;
typedef __attribute__((ext_vector_type(4))) float f32x4;
typedef __attribute__((ext_vector_type(8))) short short8;
typedef __attribute__((ext_vector_type(4))) unsigned short u16x4;
typedef __attribute__((ext_vector_type(4))) int int4v;

__device__ __forceinline__ u16 f2b(float f) {
  uint32_t u = __float_as_uint(f);
  uint32_t r = (u + 0x7fffu + ((u >> 16) & 1u)) >> 16;   // RNE
  return (u16)r;
}
__device__ __forceinline__ float b2f(u16 b) {
  return __uint_as_float(((uint32_t)b) << 16);
}
__device__ __forceinline__ float sigm(float x) { return 1.f / (1.f + __expf(-x)); }
__device__ __forceinline__ float tanh_fast(float x) {
  float e = __expf(2.f * x);
  return 1.f - 2.f / (e + 1.f);   // safe at +-inf
}
__device__ __forceinline__ void gl2lds16(const void* g, void* l) {
  __builtin_amdgcn_global_load_lds((const __attribute__((address_space(1))) void*)g,
                                   (__attribute__((address_space(3))) void*)l, 16, 0, 0);
}

// ---------------- elementwise fp32 -> bf16 (frames) ----------------
__global__ void cvt_bf16_kernel(const float* __restrict__ in, u16* __restrict__ out, int n4) {
  int i = blockIdx.x * 256 + threadIdx.x;
  if (i >= n4) return;
  float4 v = ((const float4*)in)[i];
  u16x4 o = { f2b(v.x), f2b(v.y), f2b(v.z), f2b(v.w) };
  *(u16x4*)(out + (size_t)i * 4) = o;
}

// ---------------- plain W transpose: WT[p][kc] = W[ko][p] (bf16) ----------------
// k_orig = kc < xpad ? kc : kc - (xpad - xreal); kc in [xreal,xpad) -> 0 pad
__global__ void transpose_kernel(const float* __restrict__ W, u16* __restrict__ WT,
                                 int ldin, int ldout, int xreal, int xpad) {
  __shared__ float tile[64][65];
  const int kb = blockIdx.x * 64;   // output col (k) base
  const int pb = blockIdx.y * 64;   // output row (p) base
  const int t = threadIdx.x;
  const int pc = t & 63;
  const int kr4 = t >> 6;
#pragma unroll
  for (int it = 0; it < 16; ++it) {
    int kl = kr4 + it * 4;
    int kc = kb + kl;
    int ko = kc < xpad ? kc : kc - (xpad - xreal);
    bool valid = (kc < xreal) || (kc >= xpad);
    tile[kl][pc] = valid ? W[(size_t)ko * ldin + pb + pc] : 0.f;
  }
  __syncthreads();
  const int pl = t >> 2;
  const int kq = t & 3;
#pragma unroll
  for (int half = 0; half < 2; ++half) {
    union { short8 v; u16 a[8]; } pk;
#pragma unroll
    for (int i = 0; i < 8; ++i) pk.a[i] = f2b(tile[kq * 16 + half * 8 + i][pl]);
    *(short8*)&WT[(size_t)(pb + pl) * ldout + kb + kq * 16 + half * 8] = pk.v;
  }
}

// ---------------- W_out -> B^T bf16 [384][512] (rows >=300 zero) ----------------
__global__ void woutT_kernel(const float* __restrict__ Wout, u16* __restrict__ WT) {
  int idx = blockIdx.x * 256 + threadIdx.x;
  if (idx >= 384 * 512) return;
  int n = idx >> 9, k = idx & 511;
  float v = (n < 300) ? Wout[(size_t)k * 300 + n] : 0.f;
  WT[idx] = f2b(v);
}

// ---------------- embedding gather -> A_dec bf16 [4096][320] time-major ----------------
__global__ void embed_kernel(const int* __restrict__ ids, const float* __restrict__ emb,
                             u16* __restrict__ Adec) {
  int r = blockIdx.x;              // r = t*128 + b
  int t = r >> 7, b = r & 127;
  int id = ids[b * 32 + t];
  const float* src = emb + (size_t)id * 300;
  u16* dst = Adec + (size_t)r * 320;
  for (int d = threadIdx.x; d < 320; d += 64)
    dst[d] = f2b(d < 300 ? src[d] : 0.f);
}

// ---------------- m97-style bf16 GEMM: C = A[M][K] @ BT[N][K]^T ----------------
// MODE 0: enc pre  (bf16 out, row b*64+t -> t*128+b)
// MODE 1: dec pre  (bf16 out, identity rows)
// MODE 2: out proj (fp32 out, row t*128+b -> (b*32+t)*300+w, w<300 guard)
template <int MODE>
__global__ __launch_bounds__(256)
void gemm_kernel(const u16* __restrict__ A, int lda,
                 const u16* __restrict__ BT, int ldb,
                 void* __restrict__ Cv, const float* __restrict__ bias, int K) {
  __shared__ u16 atile[128 * 32];
  __shared__ u16 btile[128 * 32];
  const int tid = threadIdx.x;
  const int wave = tid >> 6;
  const int lane = tid & 63;
  const int m0 = blockIdx.x * 128;
  const int n0 = blockIdx.y * 128;
  const int wm = wave & 1;
  const int wn = wave >> 1;
  const int colq = lane & 15;
  const int rquad = lane >> 4;

  f32x4 acc[4][4];
#pragma unroll
  for (int i = 0; i < 4; ++i)
#pragma unroll
    for (int j = 0; j < 4; ++j) { f32x4 z = {0.f, 0.f, 0.f, 0.f}; acc[i][j] = z; }

  for (int k0 = 0; k0 < K; k0 += 32) {
#pragma unroll
    for (int c = 0; c < 2; ++c) {
      const int ch = wave + c * 4;
      const int slot = ch * 64 + lane;
      const int m = slot >> 2;
      const int koff = (slot & 3) * 8;
      gl2lds16(A + (size_t)(m0 + m) * lda + k0 + koff, atile + ch * 512);
      gl2lds16(BT + (size_t)(n0 + m) * ldb + k0 + koff, btile + ch * 512);
    }
    __builtin_amdgcn_s_waitcnt(0);
    __syncthreads();
    short8 af[4], bf[4];
#pragma unroll
    for (int i = 0; i < 4; ++i)
      af[i] = *(const short8*)(atile + (wm * 64 + i * 16 + colq) * 32 + rquad * 8);
#pragma unroll
    for (int j = 0; j < 4; ++j)
      bf[j] = *(const short8*)(btile + (wn * 64 + j * 16 + colq) * 32 + rquad * 8);
#pragma unroll
    for (int i = 0; i < 4; ++i)
#pragma unroll
      for (int j = 0; j < 4; ++j)
        acc[i][j] = __builtin_amdgcn_mfma_f32_16x16x32_bf16(af[i], bf[j], acc[i][j], 0, 0, 0);
    __syncthreads();
  }

  const int gm_base = m0 + wm * 64;
  const int gn_base = n0 + wn * 64;
#pragma unroll
  for (int i = 0; i < 4; ++i) {
#pragma unroll
    for (int j = 0; j < 4; ++j) {
      const int gn = gn_base + j * 16 + colq;
      float bv;
      if (MODE == 2) bv = (gn < 300) ? bias[gn] : 0.f;
      else bv = bias[gn];
      const int rbase = gm_base + i * 16 + rquad * 4;
#pragma unroll
      for (int r = 0; r < 4; ++r) {
        const float v = acc[i][j][r] + bv;
        const int row = rbase + r;
        if (MODE == 0) {
          ((u16*)Cv)[(size_t)((row & 63) * 128 + (row >> 6)) * 2048 + gn] = f2b(v);
        } else if (MODE == 1) {
          ((u16*)Cv)[(size_t)row * 2048 + gn] = f2b(v);
        } else {
          if (gn < 300)
            ((float*)Cv)[(size_t)((row & 127) * 32 + (row >> 7)) * 300 + gn] = v;
        }
      }
    }
  }
}

// ---------------- persistent recurrent LSTM kernel ----------------
// 16 wgs x 1024 threads (16 waves = 4/SIMD). wg hg owns 32 h-cols; gates are
// BLOCKED across the 4 accumulators (l = gate), so i,j,f,o of one (row,hcol)
// live in ONE lane -> elementwise is fully in-lane (no shfl, no redundancy).
// W_h slice 128 gate-rows x 512 k bf16 in LDS for all 96 steps.
// h exchange: hbuf[s][mt:8][hg:16][r:16][16dw] bf16; canary 0xFFFFFFFF polling;
// producer: LDS stage -> 1KB-coalesced dwordx4 sc0/sc1 stores; consumer: 1KB-
// coalesced dwordx4 sc0/sc1 poll loads.
// CORRECTNESS NOTE: the canary check MUST read hv only after s_waitcnt vmcnt(0).
// The check is plain register arithmetic, so a bare waitcnt asm ("memory"
// clobber only) does NOT stop LLVM scheduling the check before it -> reads
// in-flight load dest VGPRs -> accepts canary -> NaN (round-4 failure). The
// empty asm "+v" barriers below redefine hv AFTER the waitcnt (volatile asms
// keep mutual program order), forcing check & MFMA onto post-drain values.
__global__ __launch_bounds__(1024, 4)
void lstm_recurrent_kernel(const u16* __restrict__ pre_enc,   // [64][128][2048] bf16
                           const u16* __restrict__ pre_dec,   // [32][128][2048] bf16
                           const u16* __restrict__ WencT,     // [2048][2560] bf16
                           const u16* __restrict__ WdecT,     // [2048][832]  bf16
                           int* __restrict__ hbuf,            // [97][32768] dwords
                           u16* __restrict__ dec_hs) {        // [32][128][512] bf16
  const int tid = threadIdx.x;
  const int w = tid >> 6;               // 0..15
  const int lane = tid & 63;
  const int hg = blockIdx.x;            // 0..15
  const int mt = w & 7;                 // 16-row m-tile
  const int hb = w >> 3;                // 0..1 (16-hcol half)
  const int colq = lane & 15;
  const int rquad = lane >> 4;

  __shared__ u16 wlds[128][520];        // +8 pad: 2-way-max bank aliasing
  __shared__ u16 stage[2][128][40];     // h staging, 80B row stride (16B aligned)

  {  // encoder W slice: local row lr = l*32 + c2  <->  WT row l*512 + hg*32 + c2
    for (int i = tid; i < 128 * 64; i += 1024) {
      int lr = i >> 6, cc = i & 63;
      const u16* src = WencT + (size_t)((lr >> 5) * 512 + hg * 32 + (lr & 31)) * 2560 + 2048;
      *(short8*)&wlds[lr][cc * 8] = *(const short8*)(src + cc * 8);
    }
  }
  __syncthreads();

  float cst[4] = {0.f, 0.f, 0.f, 0.f};
  const int brow = mt * 16 + rquad * 4;   // C-layout row base (r = 0..3)
  const int pbase = hg * 32 + hb * 16 + colq;   // lane's h-col (global)

  union HV { int4v i; short8 s; };

  for (int s = 0; s < 96; ++s) {
    const bool dec = (s >= 64);
    const u16* pre_t = dec ? (pre_dec + (size_t)(s - 64) * 262144)
                           : (pre_enc + (size_t)s * 262144);
    // acc init from pre-activations (plain cached loads; overlap the poll wait)
    f32x4 acc[4];
#pragma unroll
    for (int l = 0; l < 4; ++l)
#pragma unroll
      for (int r = 0; r < 4; ++r)
        acc[l][r] = b2f(pre_t[(size_t)(brow + r) * 2048 + l * 512 + pbase]);

    // poll h(s): 16 x 1KB-coalesced dwordx4 bypass loads, retry until no canary
    HV hv[16];
    const int* hread = hbuf + (size_t)s * 32768 + mt * 4096 + colq * 16 + rquad * 4;
    int bad;
    do {
#pragma unroll
      for (int g = 0; g < 4; ++g) {
        const int* hp = hread + g * 1024;
#pragma unroll
        for (int q = 0; q < 4; ++q)
          asm volatile("global_load_dwordx4 %0, %1, off offset:%2 sc0 sc1"
                       : "=v"(hv[g * 4 + q].i) : "v"(hp), "i"(q * 1024) : "memory");
      }
      asm volatile("s_waitcnt vmcnt(0)" ::: "memory");
      // register barrier: redefine hv AFTER the drain (see note above)
#pragma unroll
      for (int kt = 0; kt < 16; ++kt)
        asm volatile("" : "+v"(hv[kt].i));
      bad = 0;
#pragma unroll
      for (int kt = 0; kt < 16; ++kt)
#pragma unroll
        for (int j = 0; j < 4; ++j)
          bad |= (hv[kt].i[j] == -1) ? 1 : 0;
    } while (bad);

    // h @ W_h : A = h rows (mt tile), B = W gate-rows; l = gate index
#pragma unroll
    for (int kt = 0; kt < 16; ++kt) {
#pragma unroll
      for (int l = 0; l < 4; ++l) {
        short8 bf = *(const short8*)&wlds[l * 32 + hb * 16 + colq][kt * 32 + rquad * 8];
        acc[l] = __builtin_amdgcn_mfma_f32_16x16x32_bf16(hv[kt].s, bf, acc[l], 0, 0, 0);
      }
    }

    // elementwise: i,j,f,o all in-lane (acc[0..3][r]); 4 h values per lane
    const int sb = s & 1;
#pragma unroll
    for (int r = 0; r < 4; ++r) {
      float iv = acc[0][r], jv = acc[1][r], fv = acc[2][r], ov = acc[3][r];
      float cn = cst[r] * sigm(fv + 1.f) + sigm(iv) * tanh_fast(jv);
      cst[r] = cn;
      float hvv = tanh_fast(cn) * sigm(ov);
      stage[sb][brow + r][hb * 16 + colq] = f2b(hvv);
    }
    __syncthreads();   // stage complete (stage is double-buffered; 1 barrier/step)

    // store phase: waves 0..7 push the wg's 8KB slice, 1KB contiguous per wave
    if (tid < 512) {
      const int c = tid;                     // chunk: row=c>>2, quarter=c&3
      union { short8 v; int4v i; } vv;
      vv.v = *(const short8*)&stage[sb][c >> 2][(c & 3) * 8];
      int* dst = hbuf + (size_t)(s + 1) * 32768 + (c >> 6) * 4096 + hg * 256 +
                 ((c >> 2) & 15) * 16 + (c & 3) * 4;
      asm volatile("global_store_dwordx4 %0, %1, off sc0 sc1"
                   :: "v"(dst), "v"(vv.i) : "memory");
      if (dec)   // h(s+1) = decoder output t = s-64, plain [t*128+b][512] layout
        *(short8*)&dec_hs[(size_t)(s - 64) * 65536 + (size_t)(c >> 2) * 512 +
                          hg * 32 + (c & 3) * 8] = vv.v;
    }

    if (s == 63) {   // swap to decoder W_h (cols 320..831 of WdecT)
      for (int i = tid; i < 128 * 64; i += 1024) {
        int lr = i >> 6, cc = i & 63;
        const u16* src = WdecT + (size_t)((lr >> 5) * 512 + hg * 32 + (lr & 31)) * 832 + 320;
        *(short8*)&wlds[lr][cc * 8] = *(const short8*)(src + cc * 8);
      }
      __syncthreads();
    }
  }
  asm volatile("s_waitcnt vmcnt(0)" ::: "memory");  // drain asm stores before endpgm
}

extern "C" void kernel_launch(void* const* d_in, const int* in_sizes, int n_in,
                              void* d_out, int out_size, void* d_ws, size_t ws_size,
                              hipStream_t stream) {
  const float* frames = (const float*)d_in[0];   // [128,64,2048]
  const int* cap_ids  = (const int*)d_in[1];     // [128,32]
  const float* emb    = (const float*)d_in[2];   // [32000,300]
  const float* W_enc  = (const float*)d_in[3];   // [2560,2048]
  const float* b_enc  = (const float*)d_in[4];   // [2048]
  const float* W_dec  = (const float*)d_in[5];   // [812,2048]
  const float* b_dec  = (const float*)d_in[6];   // [2048]
  const float* W_out  = (const float*)d_in[7];   // [512,300]
  const float* b_out  = (const float*)d_in[8];   // [300]
  float* out = (float*)d_out;

  char* ws = (char*)d_ws;
  size_t off = 0;
  auto alloc = [&](size_t bytes) {
    void* p = ws + off;
    off += (bytes + 255) & ~(size_t)255;
    return p;
  };
  u16* A_enc   = (u16*)alloc(8192ull * 2048 * 2);
  u16* WencT   = (u16*)alloc(2048ull * 2560 * 2);
  u16* pre_enc = (u16*)alloc(64ull * 128 * 2048 * 2);
  u16* A_dec   = (u16*)alloc(4096ull * 320 * 2);
  u16* WdecT   = (u16*)alloc(2048ull * 832 * 2);
  u16* pre_dec = (u16*)alloc(32ull * 128 * 2048 * 2);
  u16* WoutT   = (u16*)alloc(384ull * 512 * 2);
  u16* dec_hs  = (u16*)alloc(32ull * 128 * 512 * 2);
  int* hbuf    = (int*)alloc(97ull * 32768 * 4);

  // hbuf[0] = h0 = zeros; hbuf[1..96] = 0xFFFFFFFF canary
  hipMemsetAsync(hbuf, 0, 32768ull * 4, stream);
  hipMemsetAsync(hbuf + 32768, 0xFF, 96ull * 32768 * 4, stream);

  cvt_bf16_kernel<<<16384, 256, 0, stream>>>(frames, A_enc, 4194304);
  transpose_kernel<<<dim3(40, 32), 256, 0, stream>>>(W_enc, WencT, 2048, 2560, 2048, 2048);
  transpose_kernel<<<dim3(13, 32), 256, 0, stream>>>(W_dec, WdecT, 2048, 832, 300, 320);
  woutT_kernel<<<768, 256, 0, stream>>>(W_out, WoutT);
  embed_kernel<<<4096, 64, 0, stream>>>(cap_ids, emb, A_dec);

  gemm_kernel<0><<<dim3(64, 16), 256, 0, stream>>>(A_enc, 2048, WencT, 2560, pre_enc, b_enc, 2048);
  gemm_kernel<1><<<dim3(32, 16), 256, 0, stream>>>(A_dec, 320, WdecT, 832, pre_dec, b_dec, 320);

  lstm_recurrent_kernel<<<16, 1024, 0, stream>>>(pre_enc, pre_dec, WencT, WdecT,
                                                 hbuf, dec_hs);

  gemm_kernel<2><<<dim3(32, 3), 256, 0, stream>>>(dec_hs, 512, WoutT, 512, out, b_out, 512);
}

// Round 6
// 749.651 us; speedup vs baseline: 2.3809x; 1.5713x over previous
//
#include <hip/hip_runtime.h>
#include <stdint.h>

typedef unsigned short u16;
typedef __attribute__((ext_vector_type(4))) float f32x4;
typedef __attribute__((ext_vector_type(8))) short short8;
typedef __attribute__((ext_vector_type(4))) unsigned short u16x4;
typedef __attribute__((ext_vector_type(4))) int int4v;

__device__ __forceinline__ u16 f2b(float f) {
  uint32_t u = __float_as_uint(f);
  uint32_t r = (u + 0x7fffu + ((u >> 16) & 1u)) >> 16;   // RNE
  return (u16)r;
}
__device__ __forceinline__ float b2f(u16 b) {
  return __uint_as_float(((uint32_t)b) << 16);
}
__device__ __forceinline__ float sigm(float x) { return 1.f / (1.f + __expf(-x)); }
__device__ __forceinline__ float tanh_fast(float x) {
  float e = __expf(2.f * x);
  return 1.f - 2.f / (e + 1.f);   // safe at +-inf
}
__device__ __forceinline__ void gl2lds16(const void* g, void* l) {
  __builtin_amdgcn_global_load_lds((const __attribute__((address_space(1))) void*)g,
                                   (__attribute__((address_space(3))) void*)l, 16, 0, 0);
}

// ---------------- elementwise fp32 -> bf16 (frames) ----------------
__global__ void cvt_bf16_kernel(const float* __restrict__ in, u16* __restrict__ out, int n4) {
  int i = blockIdx.x * 256 + threadIdx.x;
  if (i >= n4) return;
  float4 v = ((const float4*)in)[i];
  u16x4 o = { f2b(v.x), f2b(v.y), f2b(v.z), f2b(v.w) };
  *(u16x4*)(out + (size_t)i * 4) = o;
}

// ---------------- plain W transpose: WT[p][kc] = W[ko][p] (bf16) ----------------
// k_orig = kc < xpad ? kc : kc - (xpad - xreal); kc in [xreal,xpad) -> 0 pad
__global__ void transpose_kernel(const float* __restrict__ W, u16* __restrict__ WT,
                                 int ldin, int ldout, int xreal, int xpad) {
  __shared__ float tile[64][65];
  const int kb = blockIdx.x * 64;   // output col (k) base
  const int pb = blockIdx.y * 64;   // output row (p) base
  const int t = threadIdx.x;
  const int pc = t & 63;
  const int kr4 = t >> 6;
#pragma unroll
  for (int it = 0; it < 16; ++it) {
    int kl = kr4 + it * 4;
    int kc = kb + kl;
    int ko = kc < xpad ? kc : kc - (xpad - xreal);
    bool valid = (kc < xreal) || (kc >= xpad);
    tile[kl][pc] = valid ? W[(size_t)ko * ldin + pb + pc] : 0.f;
  }
  __syncthreads();
  const int pl = t >> 2;
  const int kq = t & 3;
#pragma unroll
  for (int half = 0; half < 2; ++half) {
    union { short8 v; u16 a[8]; } pk;
#pragma unroll
    for (int i = 0; i < 8; ++i) pk.a[i] = f2b(tile[kq * 16 + half * 8 + i][pl]);
    *(short8*)&WT[(size_t)(pb + pl) * ldout + kb + kq * 16 + half * 8] = pk.v;
  }
}

// ---------------- W_out -> B^T bf16 [384][512] (rows >=300 zero) ----------------
__global__ void woutT_kernel(const float* __restrict__ Wout, u16* __restrict__ WT) {
  int idx = blockIdx.x * 256 + threadIdx.x;
  if (idx >= 384 * 512) return;
  int n = idx >> 9, k = idx & 511;
  float v = (n < 300) ? Wout[(size_t)k * 300 + n] : 0.f;
  WT[idx] = f2b(v);
}

// ---------------- embedding gather -> A_dec bf16 [4096][320] time-major ----------------
__global__ void embed_kernel(const int* __restrict__ ids, const float* __restrict__ emb,
                             u16* __restrict__ Adec) {
  int r = blockIdx.x;              // r = t*128 + b
  int t = r >> 7, b = r & 127;
  int id = ids[b * 32 + t];
  const float* src = emb + (size_t)id * 300;
  u16* dst = Adec + (size_t)r * 320;
  for (int d = threadIdx.x; d < 320; d += 64)
    dst[d] = f2b(d < 300 ? src[d] : 0.f);
}

// ---------------- m97-style bf16 GEMM: C = A[M][K] @ BT[N][K]^T ----------------
// MODE 0: enc pre  (bf16 out, row b*64+t -> t*128+b)
// MODE 1: dec pre  (bf16 out, identity rows)
// MODE 2: out proj (fp32 out, row t*128+b -> (b*32+t)*300+w, w<300 guard)
template <int MODE>
__global__ __launch_bounds__(256)
void gemm_kernel(const u16* __restrict__ A, int lda,
                 const u16* __restrict__ BT, int ldb,
                 void* __restrict__ Cv, const float* __restrict__ bias, int K) {
  __shared__ u16 atile[128 * 32];
  __shared__ u16 btile[128 * 32];
  const int tid = threadIdx.x;
  const int wave = tid >> 6;
  const int lane = tid & 63;
  const int m0 = blockIdx.x * 128;
  const int n0 = blockIdx.y * 128;
  const int wm = wave & 1;
  const int wn = wave >> 1;
  const int colq = lane & 15;
  const int rquad = lane >> 4;

  f32x4 acc[4][4];
#pragma unroll
  for (int i = 0; i < 4; ++i)
#pragma unroll
    for (int j = 0; j < 4; ++j) { f32x4 z = {0.f, 0.f, 0.f, 0.f}; acc[i][j] = z; }

  for (int k0 = 0; k0 < K; k0 += 32) {
#pragma unroll
    for (int c = 0; c < 2; ++c) {
      const int ch = wave + c * 4;
      const int slot = ch * 64 + lane;
      const int m = slot >> 2;
      const int koff = (slot & 3) * 8;
      gl2lds16(A + (size_t)(m0 + m) * lda + k0 + koff, atile + ch * 512);
      gl2lds16(BT + (size_t)(n0 + m) * ldb + k0 + koff, btile + ch * 512);
    }
    __builtin_amdgcn_s_waitcnt(0);
    __syncthreads();
    short8 af[4], bf[4];
#pragma unroll
    for (int i = 0; i < 4; ++i)
      af[i] = *(const short8*)(atile + (wm * 64 + i * 16 + colq) * 32 + rquad * 8);
#pragma unroll
    for (int j = 0; j < 4; ++j)
      bf[j] = *(const short8*)(btile + (wn * 64 + j * 16 + colq) * 32 + rquad * 8);
#pragma unroll
    for (int i = 0; i < 4; ++i)
#pragma unroll
      for (int j = 0; j < 4; ++j)
        acc[i][j] = __builtin_amdgcn_mfma_f32_16x16x32_bf16(af[i], bf[j], acc[i][j], 0, 0, 0);
    __syncthreads();
  }

  const int gm_base = m0 + wm * 64;
  const int gn_base = n0 + wn * 64;
#pragma unroll
  for (int i = 0; i < 4; ++i) {
#pragma unroll
    for (int j = 0; j < 4; ++j) {
      const int gn = gn_base + j * 16 + colq;
      float bv;
      if (MODE == 2) bv = (gn < 300) ? bias[gn] : 0.f;
      else bv = bias[gn];
      const int rbase = gm_base + i * 16 + rquad * 4;
#pragma unroll
      for (int r = 0; r < 4; ++r) {
        const float v = acc[i][j][r] + bv;
        const int row = rbase + r;
        if (MODE == 0) {
          ((u16*)Cv)[(size_t)((row & 63) * 128 + (row >> 6)) * 2048 + gn] = f2b(v);
        } else if (MODE == 1) {
          ((u16*)Cv)[(size_t)row * 2048 + gn] = f2b(v);
        } else {
          if (gn < 300)
            ((float*)Cv)[(size_t)((row & 127) * 32 + (row >> 7)) * 300 + gn] = v;
        }
      }
    }
  }
}

// ---------------- persistent recurrent LSTM kernel ----------------
// 128 wgs x 128 threads = 8 batch-groups(16 rows) x 16 h-groups(32 cols).
// 2 waves/wg (hb = 16-col half); 1 wg/CU (133KB LDS) -> 128 active CUs, so all
// per-step throughput terms (LDS W-reads, transcendentals, MFMA issue) are 8x
// spread vs round 5. Gates BLOCKED on acc index l -> i,j,f,o in-lane, no shfl.
// W_h slice 128 gate-rows x 512 k bf16 in LDS for all 96 steps.
// h exchange: hbuf[s][bg:8][hg:16][row:16][32col bf16] (1KB producer blocks);
// canary 0xFFFFFFFF data-as-flag polling, sc0/sc1 bypass dwordx4 both ways.
// Producer store = ONE wave-instruction (64 lanes x dwordx4 = 1KB).
// CORRECTNESS NOTE: canary check must read hv only after s_waitcnt vmcnt(0);
// empty "+v" asm redefines hv post-drain (round-4 NaN lesson).
__global__ __launch_bounds__(128)
void lstm_recurrent_kernel(const u16* __restrict__ pre_enc,   // [64][128][2048] bf16
                           const u16* __restrict__ pre_dec,   // [32][128][2048] bf16
                           const u16* __restrict__ WencT,     // [2048][2560] bf16
                           const u16* __restrict__ WdecT,     // [2048][832]  bf16
                           int* __restrict__ hbuf,            // [97][32768] dwords
                           u16* __restrict__ dec_hs) {        // [32][128][512] bf16
  const int tid = threadIdx.x;
  const int lane = tid & 63;
  const int hb = tid >> 6;              // wave = 16-col half
  const int bg = blockIdx.x & 7;        // 16-row batch group
  const int hg = blockIdx.x >> 3;       // 0..15
  const int colq = lane & 15;
  const int rquad = lane >> 4;

  __shared__ u16 wlds[128][520];        // [gate-col local][k], +8 pad
  __shared__ u16 stage[2][16][32];      // h staging: 16 rows x 32 cols

  {  // encoder W slice: local row lr = l*32 + c2  <->  WT row l*512 + hg*32 + c2
    for (int i = tid; i < 128 * 64; i += 128) {
      int lr = i >> 6, cc = i & 63;
      const u16* src = WencT + (size_t)((lr >> 5) * 512 + hg * 32 + (lr & 31)) * 2560 + 2048;
      *(short8*)&wlds[lr][cc * 8] = *(const short8*)(src + cc * 8);
    }
  }
  __syncthreads();

  float cst[4] = {0.f, 0.f, 0.f, 0.f};
  const int brow = bg * 16 + rquad * 4;         // global batch row base (r = 0..3)
  const int pbase = hg * 32 + hb * 16 + colq;   // lane's h-col (global)

  union HV { int4v i; short8 s; };

  for (int s = 0; s < 96; ++s) {
    const bool dec = (s >= 64);
    const u16* pre_t = dec ? (pre_dec + (size_t)(s - 64) * 262144)
                           : (pre_enc + (size_t)s * 262144);
    // acc init from pre-activations (plain cached loads; overlap the poll wait)
    f32x4 acc[4];
#pragma unroll
    for (int l = 0; l < 4; ++l)
#pragma unroll
      for (int r = 0; r < 4; ++r)
        acc[l][r] = b2f(pre_t[(size_t)(brow + r) * 2048 + l * 512 + pbase]);

    // poll h(s): 16 x 1KB-coalesced dwordx4 bypass loads, retry until no canary
    HV hv[16];
    const int* hread = hbuf + (size_t)s * 32768 + bg * 4096 + colq * 16 + rquad * 4;
    int bad;
    do {
#pragma unroll
      for (int g = 0; g < 4; ++g) {
        const int* hp = hread + g * 1024;
#pragma unroll
        for (int q = 0; q < 4; ++q)
          asm volatile("global_load_dwordx4 %0, %1, off offset:%2 sc0 sc1"
                       : "=v"(hv[g * 4 + q].i) : "v"(hp), "i"(q * 1024) : "memory");
      }
      asm volatile("s_waitcnt vmcnt(0)" ::: "memory");
      // register barrier: redefine hv AFTER the drain (see note above)
#pragma unroll
      for (int kt = 0; kt < 16; ++kt)
        asm volatile("" : "+v"(hv[kt].i));
      bad = 0;
#pragma unroll
      for (int kt = 0; kt < 16; ++kt)
#pragma unroll
        for (int j = 0; j < 4; ++j)
          bad |= (hv[kt].i[j] == -1) ? 1 : 0;
    } while (bad);

    // h @ W_h : A = h rows (bg tile, m=colq), B = W gate-rows; l = gate index
#pragma unroll
    for (int kt = 0; kt < 16; ++kt) {
#pragma unroll
      for (int l = 0; l < 4; ++l) {
        short8 bf = *(const short8*)&wlds[l * 32 + hb * 16 + colq][kt * 32 + rquad * 8];
        acc[l] = __builtin_amdgcn_mfma_f32_16x16x32_bf16(hv[kt].s, bf, acc[l], 0, 0, 0);
      }
    }

    // elementwise: i,j,f,o all in-lane (acc[0..3][r]); 4 h values per lane
    const int sb = s & 1;
#pragma unroll
    for (int r = 0; r < 4; ++r) {
      float iv = acc[0][r], jv = acc[1][r], fv = acc[2][r], ov = acc[3][r];
      float cn = cst[r] * sigm(fv + 1.f) + sigm(iv) * tanh_fast(jv);
      cst[r] = cn;
      float hvv = tanh_fast(cn) * sigm(ov);
      stage[sb][rquad * 4 + r][hb * 16 + colq] = f2b(hvv);
    }
    __syncthreads();   // stage complete (double-buffered; one barrier per step)

    // store phase: wave 0 pushes the wg's 1KB block in ONE dwordx4 instruction
    if (tid < 64) {
      const int row = tid >> 2, q = tid & 3;
      union { short8 v; int4v i; } vv;
      vv.v = *(const short8*)&stage[sb][row][q * 8];
      int* dst = hbuf + (size_t)(s + 1) * 32768 + bg * 4096 + hg * 256 + row * 16 + q * 4;
      asm volatile("global_store_dwordx4 %0, %1, off sc0 sc1"
                   :: "v"(dst), "v"(vv.i) : "memory");
      if (dec)   // h(s+1) = decoder output t = s-64, plain [t*128+b][512] layout
        *(short8*)&dec_hs[(size_t)(s - 64) * 65536 + (size_t)(bg * 16 + row) * 512 +
                          hg * 32 + q * 8] = vv.v;
    }

    if (s == 63) {   // swap to decoder W_h (cols 320..831 of WdecT)
      for (int i = tid; i < 128 * 64; i += 128) {
        int lr = i >> 6, cc = i & 63;
        const u16* src = WdecT + (size_t)((lr >> 5) * 512 + hg * 32 + (lr & 31)) * 832 + 320;
        *(short8*)&wlds[lr][cc * 8] = *(const short8*)(src + cc * 8);
      }
      __syncthreads();
    }
  }
  asm volatile("s_waitcnt vmcnt(0)" ::: "memory");  // drain asm stores before endpgm
}

extern "C" void kernel_launch(void* const* d_in, const int* in_sizes, int n_in,
                              void* d_out, int out_size, void* d_ws, size_t ws_size,
                              hipStream_t stream) {
  const float* frames = (const float*)d_in[0];   // [128,64,2048]
  const int* cap_ids  = (const int*)d_in[1];     // [128,32]
  const float* emb    = (const float*)d_in[2];   // [32000,300]
  const float* W_enc  = (const float*)d_in[3];   // [2560,2048]
  const float* b_enc  = (const float*)d_in[4];   // [2048]
  const float* W_dec  = (const float*)d_in[5];   // [812,2048]
  const float* b_dec  = (const float*)d_in[6];   // [2048]
  const float* W_out  = (const float*)d_in[7];   // [512,300]
  const float* b_out  = (const float*)d_in[8];   // [300]
  float* out = (float*)d_out;

  char* ws = (char*)d_ws;
  size_t off = 0;
  auto alloc = [&](size_t bytes) {
    void* p = ws + off;
    off += (bytes + 255) & ~(size_t)255;
    return p;
  };
  u16* A_enc   = (u16*)alloc(8192ull * 2048 * 2);
  u16* WencT   = (u16*)alloc(2048ull * 2560 * 2);
  u16* pre_enc = (u16*)alloc(64ull * 128 * 2048 * 2);
  u16* A_dec   = (u16*)alloc(4096ull * 320 * 2);
  u16* WdecT   = (u16*)alloc(2048ull * 832 * 2);
  u16* pre_dec = (u16*)alloc(32ull * 128 * 2048 * 2);
  u16* WoutT   = (u16*)alloc(384ull * 512 * 2);
  u16* dec_hs  = (u16*)alloc(32ull * 128 * 512 * 2);
  int* hbuf    = (int*)alloc(97ull * 32768 * 4);

  // hbuf[0] = h0 = zeros; hbuf[1..96] = 0xFFFFFFFF canary
  hipMemsetAsync(hbuf, 0, 32768ull * 4, stream);
  hipMemsetAsync(hbuf + 32768, 0xFF, 96ull * 32768 * 4, stream);

  cvt_bf16_kernel<<<16384, 256, 0, stream>>>(frames, A_enc, 4194304);
  transpose_kernel<<<dim3(40, 32), 256, 0, stream>>>(W_enc, WencT, 2048, 2560, 2048, 2048);
  transpose_kernel<<<dim3(13, 32), 256, 0, stream>>>(W_dec, WdecT, 2048, 832, 300, 320);
  woutT_kernel<<<768, 256, 0, stream>>>(W_out, WoutT);
  embed_kernel<<<4096, 64, 0, stream>>>(cap_ids, emb, A_dec);

  gemm_kernel<0><<<dim3(64, 16), 256, 0, stream>>>(A_enc, 2048, WencT, 2560, pre_enc, b_enc, 2048);
  gemm_kernel<1><<<dim3(32, 16), 256, 0, stream>>>(A_dec, 320, WdecT, 832, pre_dec, b_dec, 320);

  lstm_recurrent_kernel<<<128, 128, 0, stream>>>(pre_enc, pre_dec, WencT, WdecT,
                                                 hbuf, dec_hs);

  gemm_kernel<2><<<dim3(32, 3), 256, 0, stream>>>(dec_hs, 512, WoutT, 512, out, b_out, 512);
}

// Round 7
// 688.956 us; speedup vs baseline: 2.5907x; 1.0881x over previous
//
#include <hip/hip_runtime.h>
#include <stdint.h>

typedef unsigned short u16;
typedef __attribute__((ext_vector_type(4))) float f32x4;
typedef __attribute__((ext_vector_type(8))) short short8;
typedef __attribute__((ext_vector_type(4))) unsigned short u16x4;
typedef __attribute__((ext_vector_type(4))) int int4v;

__device__ __forceinline__ u16 f2b(float f) {
  uint32_t u = __float_as_uint(f);
  uint32_t r = (u + 0x7fffu + ((u >> 16) & 1u)) >> 16;   // RNE
  return (u16)r;
}
__device__ __forceinline__ float b2f(u16 b) {
  return __uint_as_float(((uint32_t)b) << 16);
}
__device__ __forceinline__ float sigm(float x) { return 1.f / (1.f + __expf(-x)); }
__device__ __forceinline__ float tanh_fast(float x) {
  float e = __expf(2.f * x);
  return 1.f - 2.f / (e + 1.f);   // safe at +-inf
}
__device__ __forceinline__ void gl2lds16(const void* g, void* l) {
  __builtin_amdgcn_global_load_lds((const __attribute__((address_space(1))) void*)g,
                                   (__attribute__((address_space(3))) void*)l, 16, 0, 0);
}

// ---------------- elementwise fp32 -> bf16 (frames) ----------------
__global__ void cvt_bf16_kernel(const float* __restrict__ in, u16* __restrict__ out, int n4) {
  int i = blockIdx.x * 256 + threadIdx.x;
  if (i >= n4) return;
  float4 v = ((const float4*)in)[i];
  u16x4 o = { f2b(v.x), f2b(v.y), f2b(v.z), f2b(v.w) };
  *(u16x4*)(out + (size_t)i * 4) = o;
}

// ---------------- plain W transpose: WT[p][kc] = W[ko][p] (bf16) ----------------
// k_orig = kc < xpad ? kc : kc - (xpad - xreal); kc in [xreal,xpad) -> 0 pad
__global__ void transpose_kernel(const float* __restrict__ W, u16* __restrict__ WT,
                                 int ldin, int ldout, int xreal, int xpad) {
  __shared__ float tile[64][65];
  const int kb = blockIdx.x * 64;   // output col (k) base
  const int pb = blockIdx.y * 64;   // output row (p) base
  const int t = threadIdx.x;
  const int pc = t & 63;
  const int kr4 = t >> 6;
#pragma unroll
  for (int it = 0; it < 16; ++it) {
    int kl = kr4 + it * 4;
    int kc = kb + kl;
    int ko = kc < xpad ? kc : kc - (xpad - xreal);
    bool valid = (kc < xreal) || (kc >= xpad);
    tile[kl][pc] = valid ? W[(size_t)ko * ldin + pb + pc] : 0.f;
  }
  __syncthreads();
  const int pl = t >> 2;
  const int kq = t & 3;
#pragma unroll
  for (int half = 0; half < 2; ++half) {
    union { short8 v; u16 a[8]; } pk;
#pragma unroll
    for (int i = 0; i < 8; ++i) pk.a[i] = f2b(tile[kq * 16 + half * 8 + i][pl]);
    *(short8*)&WT[(size_t)(pb + pl) * ldout + kb + kq * 16 + half * 8] = pk.v;
  }
}

// ---------------- W_out -> B^T bf16 [384][512] (rows >=300 zero) ----------------
__global__ void woutT_kernel(const float* __restrict__ Wout, u16* __restrict__ WT) {
  int idx = blockIdx.x * 256 + threadIdx.x;
  if (idx >= 384 * 512) return;
  int n = idx >> 9, k = idx & 511;
  float v = (n < 300) ? Wout[(size_t)k * 300 + n] : 0.f;
  WT[idx] = f2b(v);
}

// ---------------- embedding gather -> A_dec bf16 [4096][320] time-major ----------------
__global__ void embed_kernel(const int* __restrict__ ids, const float* __restrict__ emb,
                             u16* __restrict__ Adec) {
  int r = blockIdx.x;              // r = t*128 + b
  int t = r >> 7, b = r & 127;
  int id = ids[b * 32 + t];
  const float* src = emb + (size_t)id * 300;
  u16* dst = Adec + (size_t)r * 320;
  for (int d = threadIdx.x; d < 320; d += 64)
    dst[d] = f2b(d < 300 ? src[d] : 0.f);
}

// ---------------- m97-style bf16 GEMM: C = A[M][K] @ BT[N][K]^T ----------------
// MODE 0: enc pre  (bf16 out, row b*64+t -> t*128+b)
// MODE 1: dec pre  (bf16 out, identity rows)
// MODE 2: out proj (fp32 out, row t*128+b -> (b*32+t)*300+w, w<300 guard)
template <int MODE>
__global__ __launch_bounds__(256)
void gemm_kernel(const u16* __restrict__ A, int lda,
                 const u16* __restrict__ BT, int ldb,
                 void* __restrict__ Cv, const float* __restrict__ bias, int K) {
  __shared__ u16 atile[128 * 32];
  __shared__ u16 btile[128 * 32];
  const int tid = threadIdx.x;
  const int wave = tid >> 6;
  const int lane = tid & 63;
  const int m0 = blockIdx.x * 128;
  const int n0 = blockIdx.y * 128;
  const int wm = wave & 1;
  const int wn = wave >> 1;
  const int colq = lane & 15;
  const int rquad = lane >> 4;

  f32x4 acc[4][4];
#pragma unroll
  for (int i = 0; i < 4; ++i)
#pragma unroll
    for (int j = 0; j < 4; ++j) { f32x4 z = {0.f, 0.f, 0.f, 0.f}; acc[i][j] = z; }

  for (int k0 = 0; k0 < K; k0 += 32) {
#pragma unroll
    for (int c = 0; c < 2; ++c) {
      const int ch = wave + c * 4;
      const int slot = ch * 64 + lane;
      const int m = slot >> 2;
      const int koff = (slot & 3) * 8;
      gl2lds16(A + (size_t)(m0 + m) * lda + k0 + koff, atile + ch * 512);
      gl2lds16(BT + (size_t)(n0 + m) * ldb + k0 + koff, btile + ch * 512);
    }
    __builtin_amdgcn_s_waitcnt(0);
    __syncthreads();
    short8 af[4], bf[4];
#pragma unroll
    for (int i = 0; i < 4; ++i)
      af[i] = *(const short8*)(atile + (wm * 64 + i * 16 + colq) * 32 + rquad * 8);
#pragma unroll
    for (int j = 0; j < 4; ++j)
      bf[j] = *(const short8*)(btile + (wn * 64 + j * 16 + colq) * 32 + rquad * 8);
#pragma unroll
    for (int i = 0; i < 4; ++i)
#pragma unroll
      for (int j = 0; j < 4; ++j)
        acc[i][j] = __builtin_amdgcn_mfma_f32_16x16x32_bf16(af[i], bf[j], acc[i][j], 0, 0, 0);
    __syncthreads();
  }

  const int gm_base = m0 + wm * 64;
  const int gn_base = n0 + wn * 64;
#pragma unroll
  for (int i = 0; i < 4; ++i) {
#pragma unroll
    for (int j = 0; j < 4; ++j) {
      const int gn = gn_base + j * 16 + colq;
      float bv;
      if (MODE == 2) bv = (gn < 300) ? bias[gn] : 0.f;
      else bv = bias[gn];
      const int rbase = gm_base + i * 16 + rquad * 4;
#pragma unroll
      for (int r = 0; r < 4; ++r) {
        const float v = acc[i][j][r] + bv;
        const int row = rbase + r;
        if (MODE == 0) {
          ((u16*)Cv)[(size_t)((row & 63) * 128 + (row >> 6)) * 2048 + gn] = f2b(v);
        } else if (MODE == 1) {
          ((u16*)Cv)[(size_t)row * 2048 + gn] = f2b(v);
        } else {
          if (gn < 300)
            ((float*)Cv)[(size_t)((row & 127) * 32 + (row >> 7)) * 300 + gn] = v;
        }
      }
    }
  }
}

// ---------------- persistent recurrent LSTM kernel ----------------
// 128 wgs x 128 threads = 8 batch-groups(16 rows) x 16 h-groups(32 cols).
// 2 waves/wg; 1 wg/CU (133KB LDS) -> 128 active CUs. Gates BLOCKED on acc
// index l -> i,j,f,o in-lane, no shfl. W_h slice 128x512 bf16 in LDS.
//
// Sync protocol (round 7): flag-after-drain. Producer stores its 1KB h block
// (sc0/sc1), waits vmcnt(0) (data acked at LLC), then stores flags[s+1][bg][hg]
// = 1. Consumer lanes each poll ONE flag dword (lane&15) -> wave reconverges
// only when all 16 producer flags are seen (exec-mask AND for free), then the
// 16KB data read is issued ONCE. This cuts poll traffic ~250x vs data-as-flag
// (round 6 polls were ~10 TB/s of LLC reads -> self-induced contention).
// CORRECTNESS: data loads are issued after flag observation (program order +
// LLC serialization: data was at LLC before flag store). The "+v" register
// barrier after vmcnt(0) keeps the round-4 NaN lesson (no pre-drain reads).
__global__ __launch_bounds__(128)
void lstm_recurrent_kernel(const u16* __restrict__ pre_enc,   // [64][128][2048] bf16
                           const u16* __restrict__ pre_dec,   // [32][128][2048] bf16
                           const u16* __restrict__ WencT,     // [2048][2560] bf16
                           const u16* __restrict__ WdecT,     // [2048][832]  bf16
                           int* __restrict__ hbuf,            // [97][32768] dwords
                           u16* __restrict__ dec_hs,          // [32][128][512] bf16
                           int* __restrict__ flags) {         // [97][8][16] (zeroed)
  const int tid = threadIdx.x;
  const int lane = tid & 63;
  const int hb = tid >> 6;              // wave = 16-col half
  const int bg = blockIdx.x & 7;        // 16-row batch group
  const int hg = blockIdx.x >> 3;       // 0..15
  const int colq = lane & 15;
  const int rquad = lane >> 4;

  __shared__ u16 wlds[128][520];        // [gate-col local][k], +8 pad
  __shared__ u16 stage[2][16][32];      // h staging: 16 rows x 32 cols

  {  // encoder W slice: local row lr = l*32 + c2  <->  WT row l*512 + hg*32 + c2
    for (int i = tid; i < 128 * 64; i += 128) {
      int lr = i >> 6, cc = i & 63;
      const u16* src = WencT + (size_t)((lr >> 5) * 512 + hg * 32 + (lr & 31)) * 2560 + 2048;
      *(short8*)&wlds[lr][cc * 8] = *(const short8*)(src + cc * 8);
    }
  }
  __syncthreads();

  float cst[4] = {0.f, 0.f, 0.f, 0.f};
  const int brow = bg * 16 + rquad * 4;         // global batch row base (r = 0..3)
  const int pbase = hg * 32 + hb * 16 + colq;   // lane's h-col (global)

  union HV { int4v i; short8 s; };

  for (int s = 0; s < 96; ++s) {
    const bool dec = (s >= 64);
    const u16* pre_t = dec ? (pre_dec + (size_t)(s - 64) * 262144)
                           : (pre_enc + (size_t)s * 262144);
    // acc init from pre-activations (plain cached loads; overlap the flag wait)
    f32x4 acc[4];
#pragma unroll
    for (int l = 0; l < 4; ++l)
#pragma unroll
      for (int r = 0; r < 4; ++r)
        acc[l][r] = b2f(pre_t[(size_t)(brow + r) * 2048 + l * 512 + pbase]);

    // wait for the 16 producers of this bg: one flag dword per lane
    if (s > 0) {
      const int* fp = flags + ((size_t)s * 8 + bg) * 16 + (lane & 15);
      while (__hip_atomic_load(fp, __ATOMIC_RELAXED, __HIP_MEMORY_SCOPE_AGENT) == 0) {}
      asm volatile("" ::: "memory");   // no data loads above this point
    }

    // bulk h(s) read: 16 x 1KB-coalesced dwordx4 bypass loads, issued once
    HV hv[16];
    const int* hread = hbuf + (size_t)s * 32768 + bg * 4096 + colq * 16 + rquad * 4;
#pragma unroll
    for (int g = 0; g < 4; ++g) {
      const int* hp = hread + g * 1024;
#pragma unroll
      for (int q = 0; q < 4; ++q)
        asm volatile("global_load_dwordx4 %0, %1, off offset:%2 sc0 sc1"
                     : "=v"(hv[g * 4 + q].i) : "v"(hp), "i"(q * 1024) : "memory");
    }
    asm volatile("s_waitcnt vmcnt(0)" ::: "memory");
    // register barrier: consume hv only AFTER the drain (round-4 lesson)
#pragma unroll
    for (int kt = 0; kt < 16; ++kt)
      asm volatile("" : "+v"(hv[kt].i));

    // h @ W_h : A = h rows (bg tile, m=colq), B = W gate-rows; l = gate index
#pragma unroll
    for (int kt = 0; kt < 16; ++kt) {
#pragma unroll
      for (int l = 0; l < 4; ++l) {
        short8 bf = *(const short8*)&wlds[l * 32 + hb * 16 + colq][kt * 32 + rquad * 8];
        acc[l] = __builtin_amdgcn_mfma_f32_16x16x32_bf16(hv[kt].s, bf, acc[l], 0, 0, 0);
      }
    }

    // elementwise: i,j,f,o all in-lane (acc[0..3][r]); 4 h values per lane
    const int sb = s & 1;
#pragma unroll
    for (int r = 0; r < 4; ++r) {
      float iv = acc[0][r], jv = acc[1][r], fv = acc[2][r], ov = acc[3][r];
      float cn = cst[r] * sigm(fv + 1.f) + sigm(iv) * tanh_fast(jv);
      cst[r] = cn;
      float hvv = tanh_fast(cn) * sigm(ov);
      stage[sb][rquad * 4 + r][hb * 16 + colq] = f2b(hvv);
    }
    __syncthreads();   // stage complete (double-buffered; one barrier per step)

    // store phase: wave 0 pushes the wg's 1KB block in ONE dwordx4 instruction,
    // drains it to LLC, then lane 0 sets the flag.
    if (tid < 64) {
      const int row = tid >> 2, q = tid & 3;
      union { short8 v; int4v i; } vv;
      vv.v = *(const short8*)&stage[sb][row][q * 8];
      int* dst = hbuf + (size_t)(s + 1) * 32768 + bg * 4096 + hg * 256 + row * 16 + q * 4;
      asm volatile("global_store_dwordx4 %0, %1, off sc0 sc1"
                   :: "v"(dst), "v"(vv.i) : "memory");
      if (dec)   // h(s+1) = decoder output t = s-64, plain [t*128+b][512] layout
        *(short8*)&dec_hs[(size_t)(s - 64) * 65536 + (size_t)(bg * 16 + row) * 512 +
                          hg * 32 + q * 8] = vv.v;
      asm volatile("s_waitcnt vmcnt(0)" ::: "memory");   // data acked at LLC
      if (tid == 0) {
        int* fp = flags + ((size_t)(s + 1) * 8 + bg) * 16 + hg;
        int one = 1;
        asm volatile("global_store_dword %0, %1, off sc0 sc1"
                     :: "v"(fp), "v"(one) : "memory");
      }
    }

    if (s == 63) {   // swap to decoder W_h (cols 320..831 of WdecT)
      for (int i = tid; i < 128 * 64; i += 128) {
        int lr = i >> 6, cc = i & 63;
        const u16* src = WdecT + (size_t)((lr >> 5) * 512 + hg * 32 + (lr & 31)) * 832 + 320;
        *(short8*)&wlds[lr][cc * 8] = *(const short8*)(src + cc * 8);
      }
      __syncthreads();
    }
  }
  asm volatile("s_waitcnt vmcnt(0)" ::: "memory");  // drain asm stores before endpgm
}

extern "C" void kernel_launch(void* const* d_in, const int* in_sizes, int n_in,
                              void* d_out, int out_size, void* d_ws, size_t ws_size,
                              hipStream_t stream) {
  const float* frames = (const float*)d_in[0];   // [128,64,2048]
  const int* cap_ids  = (const int*)d_in[1];     // [128,32]
  const float* emb    = (const float*)d_in[2];   // [32000,300]
  const float* W_enc  = (const float*)d_in[3];   // [2560,2048]
  const float* b_enc  = (const float*)d_in[4];   // [2048]
  const float* W_dec  = (const float*)d_in[5];   // [812,2048]
  const float* b_dec  = (const float*)d_in[6];   // [2048]
  const float* W_out  = (const float*)d_in[7];   // [512,300]
  const float* b_out  = (const float*)d_in[8];   // [300]
  float* out = (float*)d_out;

  char* ws = (char*)d_ws;
  size_t off = 0;
  auto alloc = [&](size_t bytes) {
    void* p = ws + off;
    off += (bytes + 255) & ~(size_t)255;
    return p;
  };
  u16* A_enc   = (u16*)alloc(8192ull * 2048 * 2);
  u16* WencT   = (u16*)alloc(2048ull * 2560 * 2);
  u16* pre_enc = (u16*)alloc(64ull * 128 * 2048 * 2);
  u16* A_dec   = (u16*)alloc(4096ull * 320 * 2);
  u16* WdecT   = (u16*)alloc(2048ull * 832 * 2);
  u16* pre_dec = (u16*)alloc(32ull * 128 * 2048 * 2);
  u16* WoutT   = (u16*)alloc(384ull * 512 * 2);
  u16* dec_hs  = (u16*)alloc(32ull * 128 * 512 * 2);
  int* hbuf    = (int*)alloc(97ull * 32768 * 4);
  int* flags   = (int*)alloc(97ull * 8 * 16 * 4);

  // hbuf[0] = h0 = zeros; flags all clear
  hipMemsetAsync(hbuf, 0, 32768ull * 4, stream);
  hipMemsetAsync(flags, 0, 97ull * 8 * 16 * 4, stream);

  cvt_bf16_kernel<<<16384, 256, 0, stream>>>(frames, A_enc, 4194304);
  transpose_kernel<<<dim3(40, 32), 256, 0, stream>>>(W_enc, WencT, 2048, 2560, 2048, 2048);
  transpose_kernel<<<dim3(13, 32), 256, 0, stream>>>(W_dec, WdecT, 2048, 832, 300, 320);
  woutT_kernel<<<768, 256, 0, stream>>>(W_out, WoutT);
  embed_kernel<<<4096, 64, 0, stream>>>(cap_ids, emb, A_dec);

  gemm_kernel<0><<<dim3(64, 16), 256, 0, stream>>>(A_enc, 2048, WencT, 2560, pre_enc, b_enc, 2048);
  gemm_kernel<1><<<dim3(32, 16), 256, 0, stream>>>(A_dec, 320, WdecT, 832, pre_dec, b_dec, 320);

  lstm_recurrent_kernel<<<128, 128, 0, stream>>>(pre_enc, pre_dec, WencT, WdecT,
                                                 hbuf, dec_hs, flags);

  gemm_kernel<2><<<dim3(32, 3), 256, 0, stream>>>(dec_hs, 512, WoutT, 512, out, b_out, 512);
}